// Round 5
// baseline (1694.646 us; speedup 1.0000x reference)
//
#include <hip/hip_runtime.h>

#define DD 128
#define BSHIFT 7
#define BROWS 128
#define MS_TILE 4096
#define MS_EPT 8  // edges per thread at 512 threads

typedef __attribute__((ext_vector_type(8))) short short8;
typedef __attribute__((ext_vector_type(4))) float f32x4;
typedef unsigned short u16;
typedef unsigned int u32;

__device__ __forceinline__ u16 f2bf(float f) {
  u32 u = __builtin_bit_cast(u32, f);
  u += 0x7fffu + ((u >> 16) & 1u);
  return (u16)(u >> 16);
}
__device__ __forceinline__ float bf2f(u16 s) {
  u32 u = ((u32)s) << 16;
  return __builtin_bit_cast(float, u);
}
__device__ __forceinline__ float f16val(u32 cv) {
  return (float)__builtin_bit_cast(_Float16, (u16)(cv & 0xffffu));
}
__device__ __forceinline__ float sigmoidf_(float v) { return 1.f / (1.f + __expf(-v)); }
__device__ __forceinline__ float tanhf_(float v) {
  float e = __expf(-2.f * v);
  return (1.f - e) / (1.f + e);
}

struct WPtrs { const float* w[10]; };

// Pack W [k][n] (row-major fp32, 128x128) into fragment-major bf16:
// Bp[((ks*8+nt)*64 + lane)*8 + e] = bf16( W[ks*32 + (lane>>4)*8 + e][(lane&15) + nt*16] )
__global__ void pack_weights(WPtrs wp, u16* __restrict__ bp) {
  const float* W = wp.w[blockIdx.x];
  u16* out = bp + (size_t)blockIdx.x * 16384;
  for (int o = threadIdx.x; o < 16384; o += blockDim.x) {
    int e = o & 7, lane = (o >> 3) & 63, nt = (o >> 9) & 7, ks = o >> 12;
    int k = ks * 32 + (lane >> 4) * 8 + e;
    int c = (lane & 15) + nt * 16;
    out[o] = f2bf(W[k * DD + c]);
  }
}

// LDS-staged multisplit: bucket edges by row>>BSHIFT into per-bucket spans of recs.
// rec = (col<<16 | fp16(val), row). Writes are contiguous per (tile,bucket) group.
__global__ __launch_bounds__(512) void multisplit(const int* __restrict__ rows,
                                                  const int* __restrict__ cols,
                                                  const float* __restrict__ vals,
                                                  int* __restrict__ cursor,
                                                  uint2* __restrict__ recs,
                                                  int E, int NB, int cap) {
  __shared__ u32 hist[512];
  __shared__ u32 scan_tmp[512];
  __shared__ u32 hbase[512];
  __shared__ int gbase[512];
  __shared__ u32 rankc[512];
  __shared__ uint2 stage[MS_TILE];
  const int t = threadIdx.x;
  const int tile0 = blockIdx.x * MS_TILE;
  hist[t] = 0;
  rankc[t] = 0;
  __syncthreads();
  int myb[MS_EPT];
  u32 mycv[MS_EPT], myrow[MS_EPT];
#pragma unroll
  for (int j = 0; j < MS_EPT; ++j) {
    int e = tile0 + j * 512 + t;
    if (e < E) {
      int r = rows[e];
      int b = r >> BSHIFT;
      myb[j] = b;
      myrow[j] = (u32)r;
      _Float16 hf = (_Float16)vals[e];
      mycv[j] = ((u32)cols[e] << 16) | (u32)__builtin_bit_cast(u16, hf);
      atomicAdd(&hist[b], 1u);
    } else {
      myb[j] = -1;
    }
  }
  __syncthreads();
  // exclusive scan of hist over 512 bins
  u32 v = hist[t];
  scan_tmp[t] = v;
  __syncthreads();
  for (int o = 1; o < 512; o <<= 1) {
    u32 x = (t >= o) ? scan_tmp[t - o] : 0;
    __syncthreads();
    scan_tmp[t] += x;
    __syncthreads();
  }
  hbase[t] = scan_tmp[t] - v;
  if (t < NB && v > 0) gbase[t] = atomicAdd(&cursor[t], (int)v);
  __syncthreads();
  // rank within (tile,bucket) and stage in bucket-sorted order
#pragma unroll
  for (int j = 0; j < MS_EPT; ++j) {
    if (myb[j] >= 0) {
      u32 rk = atomicAdd(&rankc[myb[j]], 1u);
      stage[hbase[myb[j]] + rk].x = mycv[j];
      stage[hbase[myb[j]] + rk].y = myrow[j];
    }
  }
  __syncthreads();
  int cnt = E - tile0;
  cnt = cnt < MS_TILE ? cnt : MS_TILE;
  for (int k = t; k < cnt; k += 512) {
    uint2 rec = stage[k];
    int b = (int)(rec.y >> BSHIFT);
    int off = gbase[b] + (k - (int)hbase[b]);
    if (off < cap) recs[(size_t)b * cap + off] = rec;
  }
}

// one block per bucket; fp32 accumulation in LDS; coalesced record reads + agg writes
__global__ __launch_bounds__(512) void spmm_bucket(const uint2* __restrict__ recs,
                                                   const int* __restrict__ cursor,
                                                   const u16* __restrict__ xb,
                                                   u16* __restrict__ aggb, int n, int cap) {
  __shared__ float acc[BROWS * DD];  // 64 KB
  const int t = threadIdx.x;
  const int lane = t & 63;
  const int wid = t >> 6;
  const int b = blockIdx.x;
  const int row0 = b << BSHIFT;
  for (int i = t; i < BROWS * DD / 4; i += 512)
    *reinterpret_cast<float4*>(&acc[i * 4]) = float4{0.f, 0.f, 0.f, 0.f};
  __syncthreads();
  int cnt = cursor[b];
  cnt = cnt < cap ? cnt : cap;
  const uint2* rb = recs + (size_t)b * cap;
  for (int chunk = wid * 64; chunk < cnt; chunk += 512) {
    int idx = chunk + lane;
    uint2 rec = (idx < cnt) ? rb[idx] : make_uint2(0u, (u32)row0);
    int ecnt = cnt - chunk;
    ecnt = ecnt < 64 ? ecnt : 64;
    int e = 0;
    for (; e + 3 < ecnt; e += 4) {
      u32 cv0 = __shfl(rec.x, e, 64), rw0 = __shfl(rec.y, e, 64);
      u32 cv1 = __shfl(rec.x, e + 1, 64), rw1 = __shfl(rec.y, e + 1, 64);
      u32 cv2 = __shfl(rec.x, e + 2, 64), rw2 = __shfl(rec.y, e + 2, 64);
      u32 cv3 = __shfl(rec.x, e + 3, 64), rw3 = __shfl(rec.y, e + 3, 64);
      u32 x0 = *reinterpret_cast<const u32*>(xb + (size_t)(cv0 >> 16) * DD + lane * 2);
      u32 x1 = *reinterpret_cast<const u32*>(xb + (size_t)(cv1 >> 16) * DD + lane * 2);
      u32 x2 = *reinterpret_cast<const u32*>(xb + (size_t)(cv2 >> 16) * DD + lane * 2);
      u32 x3 = *reinterpret_cast<const u32*>(xb + (size_t)(cv3 >> 16) * DD + lane * 2);
      float v0 = f16val(cv0), v1 = f16val(cv1), v2 = f16val(cv2), v3 = f16val(cv3);
      int a0 = ((int)(rw0 & (BROWS - 1))) * DD + lane * 2;
      int a1 = ((int)(rw1 & (BROWS - 1))) * DD + lane * 2;
      int a2 = ((int)(rw2 & (BROWS - 1))) * DD + lane * 2;
      int a3 = ((int)(rw3 & (BROWS - 1))) * DD + lane * 2;
      atomicAdd(&acc[a0], v0 * bf2f((u16)(x0 & 0xffff)));
      atomicAdd(&acc[a0 + 1], v0 * bf2f((u16)(x0 >> 16)));
      atomicAdd(&acc[a1], v1 * bf2f((u16)(x1 & 0xffff)));
      atomicAdd(&acc[a1 + 1], v1 * bf2f((u16)(x1 >> 16)));
      atomicAdd(&acc[a2], v2 * bf2f((u16)(x2 & 0xffff)));
      atomicAdd(&acc[a2 + 1], v2 * bf2f((u16)(x2 >> 16)));
      atomicAdd(&acc[a3], v3 * bf2f((u16)(x3 & 0xffff)));
      atomicAdd(&acc[a3 + 1], v3 * bf2f((u16)(x3 >> 16)));
    }
    for (; e < ecnt; ++e) {
      u32 cv = __shfl(rec.x, e, 64), rw = __shfl(rec.y, e, 64);
      u32 xw = *reinterpret_cast<const u32*>(xb + (size_t)(cv >> 16) * DD + lane * 2);
      float vv = f16val(cv);
      int a = ((int)(rw & (BROWS - 1))) * DD + lane * 2;
      atomicAdd(&acc[a], vv * bf2f((u16)(xw & 0xffff)));
      atomicAdd(&acc[a + 1], vv * bf2f((u16)(xw >> 16)));
    }
  }
  __syncthreads();
  for (int i = t; i < BROWS * 64; i += 512) {
    int rl = i >> 6, d2 = i & 63;
    int r = row0 + rl;
    if (r < n) {
      float lo = acc[rl * DD + d2 * 2];
      float hi = acc[rl * DD + d2 * 2 + 1];
      u32 o = ((u32)f2bf(hi) << 16) | (u32)f2bf(lo);
      *reinterpret_cast<u32*>(aggb + (size_t)r * DD + d2 * 2) = o;
    }
  }
}

// Fused 2-layer MLP: out = (relu(A@W1+b1))@W2 + b2, bf16 out.
// ASRC 0: A is fp32; ASRC 1: A is bf16. Per-wave private LDS tile for h1.
template <int ASRC>
__global__ __launch_bounds__(256) void mlp_fused(const void* __restrict__ Ain,
                                                 const u16* __restrict__ W1p,
                                                 const float* __restrict__ b1,
                                                 const u16* __restrict__ W2p,
                                                 const float* __restrict__ b2,
                                                 u16* __restrict__ outB, int n) {
  __shared__ u16 sm[4][32][136];
  const int lane = threadIdx.x & 63;
  const int wid = threadIdx.x >> 6;
  const int row0 = blockIdx.x * 128 + wid * 32;
  const int ar = lane & 15, ak = (lane >> 4) * 8;
  const int crow = 4 * (lane >> 4), ccol = lane & 15;

  f32x4 acc[2][8];
#pragma unroll
  for (int m = 0; m < 2; ++m)
#pragma unroll
    for (int t = 0; t < 8; ++t) acc[m][t] = f32x4{0.f, 0.f, 0.f, 0.f};

#pragma unroll
  for (int ks = 0; ks < 4; ++ks) {
    short8 a[2];
#pragma unroll
    for (int m = 0; m < 2; ++m) {
      int r = row0 + m * 16 + ar;
      r = r < n ? r : n - 1;
      if (ASRC == 0) {
        const float* Ap = (const float*)Ain + (size_t)r * DD + ks * 32 + ak;
        float4 f0 = *reinterpret_cast<const float4*>(Ap);
        float4 f1 = *reinterpret_cast<const float4*>(Ap + 4);
        short8 tv;
        tv[0] = (short)f2bf(f0.x); tv[1] = (short)f2bf(f0.y);
        tv[2] = (short)f2bf(f0.z); tv[3] = (short)f2bf(f0.w);
        tv[4] = (short)f2bf(f1.x); tv[5] = (short)f2bf(f1.y);
        tv[6] = (short)f2bf(f1.z); tv[7] = (short)f2bf(f1.w);
        a[m] = tv;
      } else {
        a[m] = *reinterpret_cast<const short8*>((const u16*)Ain + (size_t)r * DD + ks * 32 + ak);
      }
    }
#pragma unroll
    for (int nt = 0; nt < 8; ++nt) {
      short8 bfr = *reinterpret_cast<const short8*>(W1p + (((ks * 8 + nt) * 64 + lane) * 8));
#pragma unroll
      for (int m = 0; m < 2; ++m)
        acc[m][nt] = __builtin_amdgcn_mfma_f32_16x16x32_bf16(a[m], bfr, acc[m][nt], 0, 0, 0);
    }
  }
#pragma unroll
  for (int m = 0; m < 2; ++m)
#pragma unroll
    for (int nt = 0; nt < 8; ++nt) {
      float bsv = b1[ccol + nt * 16];
#pragma unroll
      for (int e = 0; e < 4; ++e) {
        float v = acc[m][nt][e] + bsv;
        v = v > 0.f ? v : 0.f;
        sm[wid][m * 16 + crow + e][ccol + nt * 16] = f2bf(v);
      }
    }
  __syncthreads();

  f32x4 acc2[2][8];
#pragma unroll
  for (int m = 0; m < 2; ++m)
#pragma unroll
    for (int t = 0; t < 8; ++t) acc2[m][t] = f32x4{0.f, 0.f, 0.f, 0.f};
#pragma unroll
  for (int ks = 0; ks < 4; ++ks) {
    short8 a2[2];
#pragma unroll
    for (int m = 0; m < 2; ++m)
      a2[m] = *reinterpret_cast<const short8*>(&sm[wid][m * 16 + ar][ks * 32 + ak]);
#pragma unroll
    for (int nt = 0; nt < 8; ++nt) {
      short8 bfr = *reinterpret_cast<const short8*>(W2p + (((ks * 8 + nt) * 64 + lane) * 8));
#pragma unroll
      for (int m = 0; m < 2; ++m)
        acc2[m][nt] = __builtin_amdgcn_mfma_f32_16x16x32_bf16(a2[m], bfr, acc2[m][nt], 0, 0, 0);
    }
  }
#pragma unroll
  for (int m = 0; m < 2; ++m)
#pragma unroll
    for (int nt = 0; nt < 8; ++nt) {
      int col = ccol + nt * 16;
      float bsv = b2[col];
#pragma unroll
      for (int e = 0; e < 4; ++e) {
        int r = row0 + m * 16 + crow + e;
        if (r < n) outB[(size_t)r * DD + col] = f2bf(acc2[m][nt][e] + bsv);
      }
    }
}

// fused 5-GEMM gates: z = sig(out@Wu1+x@Wu2+b) ; r = sig(out@Wr1+x@Wr2+b) ; oi1 = out@Wo1+bo1
__global__ __launch_bounds__(256) void gates_gemm(
    const u16* __restrict__ Ao, const u16* __restrict__ Ax, const u16* __restrict__ Wu1p,
    const u16* __restrict__ Wu2p, const u16* __restrict__ Wr1p, const u16* __restrict__ Wr2p,
    const u16* __restrict__ Wo1p, const float* __restrict__ bu1, const float* __restrict__ bu2,
    const float* __restrict__ br1, const float* __restrict__ br2, const float* __restrict__ bo1,
    u16* __restrict__ zb, u16* __restrict__ rxb, u16* __restrict__ oi1b, int n) {
  const int lane = threadIdx.x & 63;
  const int wid = threadIdx.x >> 6;
  const int row0 = blockIdx.x * 64 + wid * 16;
  f32x4 aZ[8], aR[8], aO[8];
#pragma unroll
  for (int t = 0; t < 8; ++t) {
    aZ[t] = f32x4{0.f, 0.f, 0.f, 0.f};
    aR[t] = f32x4{0.f, 0.f, 0.f, 0.f};
    aO[t] = f32x4{0.f, 0.f, 0.f, 0.f};
  }
  const int ar = lane & 15, ak = (lane >> 4) * 8;
#pragma unroll
  for (int ks = 0; ks < 4; ++ks) {
    int r = row0 + ar;
    r = r < n ? r : n - 1;
    short8 ao = *reinterpret_cast<const short8*>(Ao + (size_t)r * DD + ks * 32 + ak);
    short8 ax = *reinterpret_cast<const short8*>(Ax + (size_t)r * DD + ks * 32 + ak);
#pragma unroll
    for (int nt = 0; nt < 8; ++nt) {
      size_t bo = (size_t)(((ks * 8 + nt) * 64 + lane) * 8);
      short8 b1 = *reinterpret_cast<const short8*>(Wu1p + bo);
      short8 b2 = *reinterpret_cast<const short8*>(Wu2p + bo);
      short8 b3 = *reinterpret_cast<const short8*>(Wr1p + bo);
      short8 b4 = *reinterpret_cast<const short8*>(Wr2p + bo);
      short8 b5 = *reinterpret_cast<const short8*>(Wo1p + bo);
      aZ[nt] = __builtin_amdgcn_mfma_f32_16x16x32_bf16(ao, b1, aZ[nt], 0, 0, 0);
      aZ[nt] = __builtin_amdgcn_mfma_f32_16x16x32_bf16(ax, b2, aZ[nt], 0, 0, 0);
      aR[nt] = __builtin_amdgcn_mfma_f32_16x16x32_bf16(ao, b3, aR[nt], 0, 0, 0);
      aR[nt] = __builtin_amdgcn_mfma_f32_16x16x32_bf16(ax, b4, aR[nt], 0, 0, 0);
      aO[nt] = __builtin_amdgcn_mfma_f32_16x16x32_bf16(ao, b5, aO[nt], 0, 0, 0);
    }
  }
  const int crow = 4 * (lane >> 4), ccol = lane & 15;
#pragma unroll
  for (int nt = 0; nt < 8; ++nt) {
    int col = ccol + nt * 16;
    float bz = bu1[col] + bu2[col];
    float br_ = br1[col] + br2[col];
    float bo_ = bo1[col];
#pragma unroll
    for (int e = 0; e < 4; ++e) {
      int r = row0 + crow + e;
      if (r < n) {
        size_t idx = (size_t)r * DD + col;
        float z = sigmoidf_(aZ[nt][e] + bz);
        float rr = sigmoidf_(aR[nt][e] + br_);
        float xv = bf2f(Ax[idx]);
        zb[idx] = f2bf(z);
        rxb[idx] = f2bf(rr * xv);
        oi1b[idx] = f2bf(aO[nt][e] + bo_);
      }
    }
  }
}

// final: oi = rx@Wo2 + bo2 + oi1 ; h = tanh(oi); out = (1-z)*x + z*h
__global__ __launch_bounds__(256) void final_gemm(const u16* __restrict__ Arx,
                                                  const u16* __restrict__ Wo2p,
                                                  const float* __restrict__ bo2,
                                                  const u16* __restrict__ oi1b,
                                                  const u16* __restrict__ zb,
                                                  const u16* __restrict__ xb,
                                                  float* __restrict__ out, int n) {
  const int lane = threadIdx.x & 63;
  const int wid = threadIdx.x >> 6;
  const int row0 = blockIdx.x * 128 + wid * 32;
  f32x4 acc[2][8];
#pragma unroll
  for (int m = 0; m < 2; ++m)
#pragma unroll
    for (int t = 0; t < 8; ++t) acc[m][t] = f32x4{0.f, 0.f, 0.f, 0.f};
  const int ar = lane & 15, ak = (lane >> 4) * 8;
#pragma unroll
  for (int ks = 0; ks < 4; ++ks) {
    short8 a[2];
#pragma unroll
    for (int m = 0; m < 2; ++m) {
      int r = row0 + m * 16 + ar;
      r = r < n ? r : n - 1;
      a[m] = *reinterpret_cast<const short8*>(Arx + (size_t)r * DD + ks * 32 + ak);
    }
#pragma unroll
    for (int nt = 0; nt < 8; ++nt) {
      short8 b = *reinterpret_cast<const short8*>(Wo2p + (((ks * 8 + nt) * 64 + lane) * 8));
#pragma unroll
      for (int m = 0; m < 2; ++m)
        acc[m][nt] = __builtin_amdgcn_mfma_f32_16x16x32_bf16(a[m], b, acc[m][nt], 0, 0, 0);
    }
  }
  const int crow = 4 * (lane >> 4), ccol = lane & 15;
#pragma unroll
  for (int m = 0; m < 2; ++m) {
#pragma unroll
    for (int nt = 0; nt < 8; ++nt) {
      int col = ccol + nt * 16;
      float bsv = bo2[col];
#pragma unroll
      for (int e = 0; e < 4; ++e) {
        int r = row0 + m * 16 + crow + e;
        if (r < n) {
          size_t idx = (size_t)r * DD + col;
          float oi = acc[m][nt][e] + bsv + bf2f(oi1b[idx]);
          float h = tanhf_(oi);
          float z = bf2f(zb[idx]);
          float xv = bf2f(xb[idx]);
          out[idx] = (1.f - z) * xv + z * h;
        }
      }
    }
  }
}

extern "C" void kernel_launch(void* const* d_in, const int* in_sizes, int n_in,
                              void* d_out, int out_size, void* d_ws, size_t ws_size,
                              hipStream_t stream) {
  const int n = in_sizes[0] / DD;  // 50000
  const int E = in_sizes[1];       // 1.6M
  const float* x_in = (const float*)d_in[0];
  const int* rows = (const int*)d_in[1];
  const int* cols = (const int*)d_in[2];
  const float* vals = (const float*)d_in[3];
  const float* Wm[10];
  const float* Bm[10];
  for (int i = 0; i < 10; ++i) {
    Wm[i] = (const float*)d_in[4 + 2 * i];
    Bm[i] = (const float*)d_in[5 + 2 * i];
  }

  const int NB = (n + BROWS - 1) >> BSHIFT;           // 391
  const int cap = (((E / NB) * 5) / 4 + 511) & ~511;  // ~5120, 16-sigma slack

  char* base = (char*)d_ws;
  size_t off = 0;
  auto alloc = [&](size_t bytes) -> char* {
    char* p = base + off;
    off += (bytes + 255) & ~(size_t)255;
    return p;
  };
  u16* wpack = (u16*)alloc((size_t)10 * 16384 * 2);
  u16* x_b = (u16*)alloc((size_t)n * DD * 2);
  u16* agg_b = (u16*)alloc((size_t)n * DD * 2);  // reused as out_b
  u16* z_b = (u16*)alloc((size_t)n * DD * 2);
  u16* oi1_b = (u16*)alloc((size_t)n * DD * 2);
  u16* rx_b = (u16*)alloc((size_t)n * DD * 2);
  int* cursor = (int*)alloc((size_t)NB * 4);
  uint2* recs = (uint2*)alloc((size_t)NB * cap * 8);
  (void)ws_size;
  (void)n_in;
  (void)out_size;

  hipMemsetAsync(cursor, 0, (size_t)NB * 4, stream);
  WPtrs wp;
  for (int i = 0; i < 10; ++i) wp.w[i] = Wm[i];
  pack_weights<<<10, 256, 0, stream>>>(wp, wpack);
  // bucket the edges (replaces count+scan+permute)
  multisplit<<<(E + MS_TILE - 1) / MS_TILE, 512, 0, stream>>>(rows, cols, vals, cursor, recs, E,
                                                             NB, cap);
  int gblocks = (n + 127) / 128;
  // x = mlp2(x_in, m1_*)  (fp32 input, fused 2-layer)
  mlp_fused<0><<<gblocks, 256, 0, stream>>>(x_in, wpack + 0 * 16384, Bm[0], wpack + 1 * 16384,
                                            Bm[1], x_b, n);
  // agg = segment_sum(vals * x[cols], rows)  (bucketed, LDS fp32 accum)
  spmm_bucket<<<NB, 512, 0, stream>>>(recs, cursor, x_b, agg_b, n, cap);
  // out = mlp2(agg, m2_*)  (bf16 input, fused 2-layer)
  mlp_fused<1><<<gblocks, 256, 0, stream>>>(agg_b, wpack + 2 * 16384, Bm[2], wpack + 3 * 16384,
                                            Bm[3], agg_b, n);
  // gates
  gates_gemm<<<(n + 63) / 64, 256, 0, stream>>>(
      agg_b, x_b, wpack + 4 * 16384, wpack + 5 * 16384, wpack + 6 * 16384, wpack + 7 * 16384,
      wpack + 8 * 16384, Bm[4], Bm[5], Bm[6], Bm[7], Bm[8], z_b, rx_b, oi1_b, n);
  // final
  final_gemm<<<gblocks, 256, 0, stream>>>(rx_b, wpack + 9 * 16384, Bm[9], oi1_b, z_b, x_b,
                                          (float*)d_out, n);
}

// Round 6
// 360.402 us; speedup vs baseline: 4.7021x; 4.7021x over previous
//
#include <hip/hip_runtime.h>

#define DD 128
#define BSHIFT 7
#define BROWS 128
#define MS_TILE 4096
#define MS_EPT 8       // edges per thread at 512 threads
#define STAGE_CAP 6144 // bucket_csr LDS stage capacity (>= cap)

typedef __attribute__((ext_vector_type(8))) short short8;
typedef __attribute__((ext_vector_type(4))) float f32x4;
typedef unsigned short u16;
typedef unsigned int u32;

__device__ __forceinline__ u16 f2bf(float f) {
  u32 u = __builtin_bit_cast(u32, f);
  u += 0x7fffu + ((u >> 16) & 1u);
  return (u16)(u >> 16);
}
__device__ __forceinline__ float bf2f(u16 s) {
  u32 u = ((u32)s) << 16;
  return __builtin_bit_cast(float, u);
}
__device__ __forceinline__ float f16val(u32 cv) {
  return (float)__builtin_bit_cast(_Float16, (u16)(cv & 0xffffu));
}
__device__ __forceinline__ float sigmoidf_(float v) { return 1.f / (1.f + __expf(-v)); }
__device__ __forceinline__ float tanhf_(float v) {
  float e = __expf(-2.f * v);
  return (1.f - e) / (1.f + e);
}

struct WPtrs { const float* w[10]; };

// Pack W [k][n] (row-major fp32, 128x128) into fragment-major bf16:
// Bp[((ks*8+nt)*64 + lane)*8 + e] = bf16( W[ks*32 + (lane>>4)*8 + e][(lane&15) + nt*16] )
__global__ void pack_weights(WPtrs wp, u16* __restrict__ bp) {
  const float* W = wp.w[blockIdx.x];
  u16* out = bp + (size_t)blockIdx.x * 16384;
  for (int o = threadIdx.x; o < 16384; o += blockDim.x) {
    int e = o & 7, lane = (o >> 3) & 63, nt = (o >> 9) & 7, ks = o >> 12;
    int k = ks * 32 + (lane >> 4) * 8 + e;
    int c = (lane & 15) + nt * 16;
    out[o] = f2bf(W[k * DD + c]);
  }
}

// LDS-staged multisplit: bucket edges by row>>BSHIFT into per-bucket spans of recs.
// rec = (col<<16 | fp16(val), row). Writes are contiguous per (tile,bucket) group.
__global__ __launch_bounds__(512) void multisplit(const int* __restrict__ rows,
                                                  const int* __restrict__ cols,
                                                  const float* __restrict__ vals,
                                                  int* __restrict__ cursor,
                                                  uint2* __restrict__ recs,
                                                  int E, int NB, int cap) {
  __shared__ u32 hist[512];
  __shared__ u32 scan_tmp[512];
  __shared__ u32 hbase[512];
  __shared__ int gbase[512];
  __shared__ u32 rankc[512];
  __shared__ uint2 stage[MS_TILE];
  const int t = threadIdx.x;
  const int tile0 = blockIdx.x * MS_TILE;
  hist[t] = 0;
  rankc[t] = 0;
  __syncthreads();
  int myb[MS_EPT];
  u32 mycv[MS_EPT], myrow[MS_EPT];
#pragma unroll
  for (int j = 0; j < MS_EPT; ++j) {
    int e = tile0 + j * 512 + t;
    if (e < E) {
      int r = rows[e];
      int b = r >> BSHIFT;
      myb[j] = b;
      myrow[j] = (u32)r;
      _Float16 hf = (_Float16)vals[e];
      mycv[j] = ((u32)cols[e] << 16) | (u32)__builtin_bit_cast(u16, hf);
      atomicAdd(&hist[b], 1u);
    } else {
      myb[j] = -1;
    }
  }
  __syncthreads();
  // exclusive scan of hist over 512 bins
  u32 v = hist[t];
  scan_tmp[t] = v;
  __syncthreads();
  for (int o = 1; o < 512; o <<= 1) {
    u32 x = (t >= o) ? scan_tmp[t - o] : 0;
    __syncthreads();
    scan_tmp[t] += x;
    __syncthreads();
  }
  hbase[t] = scan_tmp[t] - v;
  if (t < NB && v > 0) gbase[t] = atomicAdd(&cursor[t], (int)v);
  __syncthreads();
  // rank within (tile,bucket) and stage in bucket-sorted order
#pragma unroll
  for (int j = 0; j < MS_EPT; ++j) {
    if (myb[j] >= 0) {
      u32 rk = atomicAdd(&rankc[myb[j]], 1u);
      stage[hbase[myb[j]] + rk].x = mycv[j];
      stage[hbase[myb[j]] + rk].y = myrow[j];
    }
  }
  __syncthreads();
  int cnt = E - tile0;
  cnt = cnt < MS_TILE ? cnt : MS_TILE;
  for (int k = t; k < cnt; k += 512) {
    uint2 rec = stage[k];
    int b = (int)(rec.y >> BSHIFT);
    int off = gbase[b] + (k - (int)hbase[b]);
    if (off < cap) recs[(size_t)b * cap + off] = rec;
  }
}

// Per-bucket CSR: row-sort the bucket's records in LDS, write coalesced 4B records
// plus per-row start/count. One block per bucket.
__global__ __launch_bounds__(512) void bucket_csr(const uint2* __restrict__ recs,
                                                  const int* __restrict__ cursor,
                                                  u32* __restrict__ recs2,
                                                  int* __restrict__ rowstart,
                                                  int* __restrict__ rowcnt, int n, int cap) {
  __shared__ int hist[BROWS];
  __shared__ int sc[BROWS];
  __shared__ int hbase[BROWS];
  __shared__ u32 rank[BROWS];
  __shared__ u32 stage[STAGE_CAP];
  const int t = threadIdx.x;
  const int b = blockIdx.x;
  int cnt = cursor[b];
  cnt = cnt < cap ? cnt : cap;
  const uint2* rb = recs + (size_t)b * cap;
  if (t < BROWS) { hist[t] = 0; rank[t] = 0; }
  __syncthreads();
  for (int i = t; i < cnt; i += 512) atomicAdd(&hist[rb[i].y & (BROWS - 1)], 1);
  __syncthreads();
  // exclusive scan over 128 bins
  if (t < BROWS) sc[t] = hist[t];
  __syncthreads();
  for (int o = 1; o < BROWS; o <<= 1) {
    int x = (t >= o && t < BROWS) ? sc[t - o] : 0;
    __syncthreads();
    if (t < BROWS) sc[t] += x;
    __syncthreads();
  }
  if (t < BROWS) {
    hbase[t] = sc[t] - hist[t];
    int r = (b << BSHIFT) + t;
    if (r < n) {
      rowstart[r] = b * cap + hbase[t];
      rowcnt[r] = hist[t];
    }
  }
  __syncthreads();
  for (int i = t; i < cnt; i += 512) {
    uint2 rec = rb[i];
    int lr = (int)(rec.y & (BROWS - 1));
    u32 p = atomicAdd(&rank[lr], 1u);
    stage[hbase[lr] + p] = rec.x;
  }
  __syncthreads();
  u32* ob = recs2 + (size_t)b * cap;
  for (int i = t; i < cnt; i += 512) ob[i] = stage[i];
}

// one wave per row; lane handles 2 consecutive d's (one 256B row per gather);
// register accumulation, no shfl/LDS in the gather loop.
__global__ void spmm_agg(const int* __restrict__ rowstart, const int* __restrict__ rowcnt,
                         const u32* __restrict__ recs2, const u16* __restrict__ xb,
                         u16* __restrict__ aggb, int n) {
  int row = blockIdx.x * 4 + (threadIdx.x >> 6);
  int lane = threadIdx.x & 63;
  if (row >= n) return;
  int s = rowstart[row];
  int e2 = s + rowcnt[row];
  float a0 = 0.f, a1 = 0.f;
  int j = s;
  for (; j + 3 < e2; j += 4) {
    u32 pk0 = recs2[j], pk1 = recs2[j + 1], pk2 = recs2[j + 2], pk3 = recs2[j + 3];
    u32 x0 = *reinterpret_cast<const u32*>(xb + (size_t)(pk0 >> 16) * DD + lane * 2);
    u32 x1 = *reinterpret_cast<const u32*>(xb + (size_t)(pk1 >> 16) * DD + lane * 2);
    u32 x2 = *reinterpret_cast<const u32*>(xb + (size_t)(pk2 >> 16) * DD + lane * 2);
    u32 x3 = *reinterpret_cast<const u32*>(xb + (size_t)(pk3 >> 16) * DD + lane * 2);
    float v0 = f16val(pk0), v1 = f16val(pk1), v2 = f16val(pk2), v3 = f16val(pk3);
    a0 += v0 * bf2f((u16)(x0 & 0xffff)) + v1 * bf2f((u16)(x1 & 0xffff)) +
          v2 * bf2f((u16)(x2 & 0xffff)) + v3 * bf2f((u16)(x3 & 0xffff));
    a1 += v0 * bf2f((u16)(x0 >> 16)) + v1 * bf2f((u16)(x1 >> 16)) +
          v2 * bf2f((u16)(x2 >> 16)) + v3 * bf2f((u16)(x3 >> 16));
  }
  for (; j < e2; ++j) {
    u32 pk = recs2[j];
    u32 x0 = *reinterpret_cast<const u32*>(xb + (size_t)(pk >> 16) * DD + lane * 2);
    float v0 = f16val(pk);
    a0 += v0 * bf2f((u16)(x0 & 0xffff));
    a1 += v0 * bf2f((u16)(x0 >> 16));
  }
  u32 o = ((u32)f2bf(a1) << 16) | (u32)f2bf(a0);
  *reinterpret_cast<u32*>(aggb + (size_t)row * DD + lane * 2) = o;
}

// Fused 2-layer MLP: out = (relu(A@W1+b1))@W2 + b2, bf16 out.
// ASRC 0: A is fp32; ASRC 1: A is bf16. Per-wave private LDS tile for h1.
template <int ASRC>
__global__ __launch_bounds__(256) void mlp_fused(const void* __restrict__ Ain,
                                                 const u16* __restrict__ W1p,
                                                 const float* __restrict__ b1,
                                                 const u16* __restrict__ W2p,
                                                 const float* __restrict__ b2,
                                                 u16* __restrict__ outB, int n) {
  __shared__ u16 sm[4][32][136];
  const int lane = threadIdx.x & 63;
  const int wid = threadIdx.x >> 6;
  const int row0 = blockIdx.x * 128 + wid * 32;
  const int ar = lane & 15, ak = (lane >> 4) * 8;
  const int crow = 4 * (lane >> 4), ccol = lane & 15;

  f32x4 acc[2][8];
#pragma unroll
  for (int m = 0; m < 2; ++m)
#pragma unroll
    for (int t = 0; t < 8; ++t) acc[m][t] = f32x4{0.f, 0.f, 0.f, 0.f};

#pragma unroll
  for (int ks = 0; ks < 4; ++ks) {
    short8 a[2];
#pragma unroll
    for (int m = 0; m < 2; ++m) {
      int r = row0 + m * 16 + ar;
      r = r < n ? r : n - 1;
      if (ASRC == 0) {
        const float* Ap = (const float*)Ain + (size_t)r * DD + ks * 32 + ak;
        float4 f0 = *reinterpret_cast<const float4*>(Ap);
        float4 f1 = *reinterpret_cast<const float4*>(Ap + 4);
        short8 tv;
        tv[0] = (short)f2bf(f0.x); tv[1] = (short)f2bf(f0.y);
        tv[2] = (short)f2bf(f0.z); tv[3] = (short)f2bf(f0.w);
        tv[4] = (short)f2bf(f1.x); tv[5] = (short)f2bf(f1.y);
        tv[6] = (short)f2bf(f1.z); tv[7] = (short)f2bf(f1.w);
        a[m] = tv;
      } else {
        a[m] = *reinterpret_cast<const short8*>((const u16*)Ain + (size_t)r * DD + ks * 32 + ak);
      }
    }
#pragma unroll
    for (int nt = 0; nt < 8; ++nt) {
      short8 bfr = *reinterpret_cast<const short8*>(W1p + (((ks * 8 + nt) * 64 + lane) * 8));
#pragma unroll
      for (int m = 0; m < 2; ++m)
        acc[m][nt] = __builtin_amdgcn_mfma_f32_16x16x32_bf16(a[m], bfr, acc[m][nt], 0, 0, 0);
    }
  }
#pragma unroll
  for (int m = 0; m < 2; ++m)
#pragma unroll
    for (int nt = 0; nt < 8; ++nt) {
      float bsv = b1[ccol + nt * 16];
#pragma unroll
      for (int e = 0; e < 4; ++e) {
        float v = acc[m][nt][e] + bsv;
        v = v > 0.f ? v : 0.f;
        sm[wid][m * 16 + crow + e][ccol + nt * 16] = f2bf(v);
      }
    }
  __syncthreads();

  f32x4 acc2[2][8];
#pragma unroll
  for (int m = 0; m < 2; ++m)
#pragma unroll
    for (int t = 0; t < 8; ++t) acc2[m][t] = f32x4{0.f, 0.f, 0.f, 0.f};
#pragma unroll
  for (int ks = 0; ks < 4; ++ks) {
    short8 a2[2];
#pragma unroll
    for (int m = 0; m < 2; ++m)
      a2[m] = *reinterpret_cast<const short8*>(&sm[wid][m * 16 + ar][ks * 32 + ak]);
#pragma unroll
    for (int nt = 0; nt < 8; ++nt) {
      short8 bfr = *reinterpret_cast<const short8*>(W2p + (((ks * 8 + nt) * 64 + lane) * 8));
#pragma unroll
      for (int m = 0; m < 2; ++m)
        acc2[m][nt] = __builtin_amdgcn_mfma_f32_16x16x32_bf16(a2[m], bfr, acc2[m][nt], 0, 0, 0);
    }
  }
#pragma unroll
  for (int m = 0; m < 2; ++m)
#pragma unroll
    for (int nt = 0; nt < 8; ++nt) {
      int col = ccol + nt * 16;
      float bsv = b2[col];
#pragma unroll
      for (int e = 0; e < 4; ++e) {
        int r = row0 + m * 16 + crow + e;
        if (r < n) outB[(size_t)r * DD + col] = f2bf(acc2[m][nt][e] + bsv);
      }
    }
}

// fused 5-GEMM gates: z = sig(out@Wu1+x@Wu2+b) ; r = sig(out@Wr1+x@Wr2+b) ; oi1 = out@Wo1+bo1
__global__ __launch_bounds__(256) void gates_gemm(
    const u16* __restrict__ Ao, const u16* __restrict__ Ax, const u16* __restrict__ Wu1p,
    const u16* __restrict__ Wu2p, const u16* __restrict__ Wr1p, const u16* __restrict__ Wr2p,
    const u16* __restrict__ Wo1p, const float* __restrict__ bu1, const float* __restrict__ bu2,
    const float* __restrict__ br1, const float* __restrict__ br2, const float* __restrict__ bo1,
    u16* __restrict__ zb, u16* __restrict__ rxb, u16* __restrict__ oi1b, int n) {
  const int lane = threadIdx.x & 63;
  const int wid = threadIdx.x >> 6;
  const int row0 = blockIdx.x * 64 + wid * 16;
  f32x4 aZ[8], aR[8], aO[8];
#pragma unroll
  for (int t = 0; t < 8; ++t) {
    aZ[t] = f32x4{0.f, 0.f, 0.f, 0.f};
    aR[t] = f32x4{0.f, 0.f, 0.f, 0.f};
    aO[t] = f32x4{0.f, 0.f, 0.f, 0.f};
  }
  const int ar = lane & 15, ak = (lane >> 4) * 8;
#pragma unroll
  for (int ks = 0; ks < 4; ++ks) {
    int r = row0 + ar;
    r = r < n ? r : n - 1;
    short8 ao = *reinterpret_cast<const short8*>(Ao + (size_t)r * DD + ks * 32 + ak);
    short8 ax = *reinterpret_cast<const short8*>(Ax + (size_t)r * DD + ks * 32 + ak);
#pragma unroll
    for (int nt = 0; nt < 8; ++nt) {
      size_t bo = (size_t)(((ks * 8 + nt) * 64 + lane) * 8);
      short8 b1 = *reinterpret_cast<const short8*>(Wu1p + bo);
      short8 b2 = *reinterpret_cast<const short8*>(Wu2p + bo);
      short8 b3 = *reinterpret_cast<const short8*>(Wr1p + bo);
      short8 b4 = *reinterpret_cast<const short8*>(Wr2p + bo);
      short8 b5 = *reinterpret_cast<const short8*>(Wo1p + bo);
      aZ[nt] = __builtin_amdgcn_mfma_f32_16x16x32_bf16(ao, b1, aZ[nt], 0, 0, 0);
      aZ[nt] = __builtin_amdgcn_mfma_f32_16x16x32_bf16(ax, b2, aZ[nt], 0, 0, 0);
      aR[nt] = __builtin_amdgcn_mfma_f32_16x16x32_bf16(ao, b3, aR[nt], 0, 0, 0);
      aR[nt] = __builtin_amdgcn_mfma_f32_16x16x32_bf16(ax, b4, aR[nt], 0, 0, 0);
      aO[nt] = __builtin_amdgcn_mfma_f32_16x16x32_bf16(ao, b5, aO[nt], 0, 0, 0);
    }
  }
  const int crow = 4 * (lane >> 4), ccol = lane & 15;
#pragma unroll
  for (int nt = 0; nt < 8; ++nt) {
    int col = ccol + nt * 16;
    float bz = bu1[col] + bu2[col];
    float br_ = br1[col] + br2[col];
    float bo_ = bo1[col];
#pragma unroll
    for (int e = 0; e < 4; ++e) {
      int r = row0 + crow + e;
      if (r < n) {
        size_t idx = (size_t)r * DD + col;
        float z = sigmoidf_(aZ[nt][e] + bz);
        float rr = sigmoidf_(aR[nt][e] + br_);
        float xv = bf2f(Ax[idx]);
        zb[idx] = f2bf(z);
        rxb[idx] = f2bf(rr * xv);
        oi1b[idx] = f2bf(aO[nt][e] + bo_);
      }
    }
  }
}

// final: oi = rx@Wo2 + bo2 + oi1 ; h = tanh(oi); out = (1-z)*x + z*h
__global__ __launch_bounds__(256) void final_gemm(const u16* __restrict__ Arx,
                                                  const u16* __restrict__ Wo2p,
                                                  const float* __restrict__ bo2,
                                                  const u16* __restrict__ oi1b,
                                                  const u16* __restrict__ zb,
                                                  const u16* __restrict__ xb,
                                                  float* __restrict__ out, int n) {
  const int lane = threadIdx.x & 63;
  const int wid = threadIdx.x >> 6;
  const int row0 = blockIdx.x * 128 + wid * 32;
  f32x4 acc[2][8];
#pragma unroll
  for (int m = 0; m < 2; ++m)
#pragma unroll
    for (int t = 0; t < 8; ++t) acc[m][t] = f32x4{0.f, 0.f, 0.f, 0.f};
  const int ar = lane & 15, ak = (lane >> 4) * 8;
#pragma unroll
  for (int ks = 0; ks < 4; ++ks) {
    short8 a[2];
#pragma unroll
    for (int m = 0; m < 2; ++m) {
      int r = row0 + m * 16 + ar;
      r = r < n ? r : n - 1;
      a[m] = *reinterpret_cast<const short8*>(Arx + (size_t)r * DD + ks * 32 + ak);
    }
#pragma unroll
    for (int nt = 0; nt < 8; ++nt) {
      short8 b = *reinterpret_cast<const short8*>(Wo2p + (((ks * 8 + nt) * 64 + lane) * 8));
#pragma unroll
      for (int m = 0; m < 2; ++m)
        acc[m][nt] = __builtin_amdgcn_mfma_f32_16x16x32_bf16(a[m], b, acc[m][nt], 0, 0, 0);
    }
  }
  const int crow = 4 * (lane >> 4), ccol = lane & 15;
#pragma unroll
  for (int m = 0; m < 2; ++m) {
#pragma unroll
    for (int nt = 0; nt < 8; ++nt) {
      int col = ccol + nt * 16;
      float bsv = bo2[col];
#pragma unroll
      for (int e = 0; e < 4; ++e) {
        int r = row0 + m * 16 + crow + e;
        if (r < n) {
          size_t idx = (size_t)r * DD + col;
          float oi = acc[m][nt][e] + bsv + bf2f(oi1b[idx]);
          float h = tanhf_(oi);
          float z = bf2f(zb[idx]);
          float xv = bf2f(xb[idx]);
          out[idx] = (1.f - z) * xv + z * h;
        }
      }
    }
  }
}

extern "C" void kernel_launch(void* const* d_in, const int* in_sizes, int n_in,
                              void* d_out, int out_size, void* d_ws, size_t ws_size,
                              hipStream_t stream) {
  const int n = in_sizes[0] / DD;  // 50000
  const int E = in_sizes[1];       // 1.6M
  const float* x_in = (const float*)d_in[0];
  const int* rows = (const int*)d_in[1];
  const int* cols = (const int*)d_in[2];
  const float* vals = (const float*)d_in[3];
  const float* Wm[10];
  const float* Bm[10];
  for (int i = 0; i < 10; ++i) {
    Wm[i] = (const float*)d_in[4 + 2 * i];
    Bm[i] = (const float*)d_in[5 + 2 * i];
  }

  const int NB = (n + BROWS - 1) >> BSHIFT;           // 391
  int cap = (((E / NB) * 5) / 4 + 511) & ~511;        // ~5120, 16-sigma slack
  cap = cap < STAGE_CAP ? cap : STAGE_CAP;

  char* base = (char*)d_ws;
  size_t off = 0;
  auto alloc = [&](size_t bytes) -> char* {
    char* p = base + off;
    off += (bytes + 255) & ~(size_t)255;
    return p;
  };
  u16* wpack = (u16*)alloc((size_t)10 * 16384 * 2);
  u16* x_b = (u16*)alloc((size_t)n * DD * 2);
  u16* agg_b = (u16*)alloc((size_t)n * DD * 2);  // reused as out_b
  u16* z_b = (u16*)alloc((size_t)n * DD * 2);
  u16* oi1_b = (u16*)alloc((size_t)n * DD * 2);
  u16* rx_b = (u16*)alloc((size_t)n * DD * 2);
  int* cursor = (int*)alloc((size_t)NB * 4);
  int* rowstart = (int*)alloc((size_t)n * 4);
  int* rowcnt = (int*)alloc((size_t)n * 4);
  uint2* recs = (uint2*)alloc((size_t)NB * cap * 8);
  u32* recs2 = (u32*)alloc((size_t)NB * cap * 4);
  (void)ws_size;
  (void)n_in;
  (void)out_size;

  hipMemsetAsync(cursor, 0, (size_t)NB * 4, stream);
  WPtrs wp;
  for (int i = 0; i < 10; ++i) wp.w[i] = Wm[i];
  pack_weights<<<10, 256, 0, stream>>>(wp, wpack);
  // bucket the edges (coalesced writes)
  multisplit<<<(E + MS_TILE - 1) / MS_TILE, 512, 0, stream>>>(rows, cols, vals, cursor, recs, E,
                                                             NB, cap);
  // row-sort each bucket in LDS -> per-row CSR with coalesced writes
  bucket_csr<<<NB, 512, 0, stream>>>(recs, cursor, recs2, rowstart, rowcnt, n, cap);
  int gblocks = (n + 127) / 128;
  // x = mlp2(x_in, m1_*)  (fp32 input, fused 2-layer)
  mlp_fused<0><<<gblocks, 256, 0, stream>>>(x_in, wpack + 0 * 16384, Bm[0], wpack + 1 * 16384,
                                            Bm[1], x_b, n);
  // agg = segment_sum(vals * x[cols], rows)  (wave-per-row, register accum)
  spmm_agg<<<(n + 3) / 4, 256, 0, stream>>>(rowstart, rowcnt, recs2, x_b, agg_b, n);
  // out = mlp2(agg, m2_*)  (bf16 input, fused 2-layer)
  mlp_fused<1><<<gblocks, 256, 0, stream>>>(agg_b, wpack + 2 * 16384, Bm[2], wpack + 3 * 16384,
                                            Bm[3], agg_b, n);
  // gates
  gates_gemm<<<(n + 63) / 64, 256, 0, stream>>>(
      agg_b, x_b, wpack + 4 * 16384, wpack + 5 * 16384, wpack + 6 * 16384, wpack + 7 * 16384,
      wpack + 8 * 16384, Bm[4], Bm[5], Bm[6], Bm[7], Bm[8], z_b, rx_b, oi1_b, n);
  // final
  final_gemm<<<gblocks, 256, 0, stream>>>(rx_b, wpack + 9 * 16384, Bm[9], oi1_b, z_b, x_b,
                                          (float*)d_out, n);
}

// Round 7
// 357.115 us; speedup vs baseline: 4.7454x; 1.0092x over previous
//
#include <hip/hip_runtime.h>

#define DD 128
#define BSHIFT 7
#define BROWS 128
#define MS_TILE 4096
#define MS_EPT 8       // edges per thread at 512 threads
#define STAGE_CAP 6144 // bucket_csr LDS stage capacity (>= cap)

typedef __attribute__((ext_vector_type(8))) short short8;
typedef __attribute__((ext_vector_type(4))) float f32x4;
typedef unsigned short u16;
typedef unsigned int u32;

__device__ __forceinline__ u16 f2bf(float f) {
  u32 u = __builtin_bit_cast(u32, f);
  u += 0x7fffu + ((u >> 16) & 1u);
  return (u16)(u >> 16);
}
__device__ __forceinline__ float bf2f(u16 s) {
  u32 u = ((u32)s) << 16;
  return __builtin_bit_cast(float, u);
}
__device__ __forceinline__ float f16val(u32 cv) {
  return (float)__builtin_bit_cast(_Float16, (u16)(cv & 0xffffu));
}
__device__ __forceinline__ float sigmoidf_(float v) { return 1.f / (1.f + __expf(-v)); }
__device__ __forceinline__ float tanhf_(float v) {
  float e = __expf(-2.f * v);
  return (1.f - e) / (1.f + e);
}

struct WPtrs { const float* w[10]; };

// Pack W [k][n] (row-major fp32, 128x128) into fragment-major bf16:
// Bp[((ks*8+nt)*64 + lane)*8 + e] = bf16( W[ks*32 + (lane>>4)*8 + e][(lane&15) + nt*16] )
__global__ void pack_weights(WPtrs wp, u16* __restrict__ bp) {
  const float* W = wp.w[blockIdx.x];
  u16* out = bp + (size_t)blockIdx.x * 16384;
  for (int o = threadIdx.x; o < 16384; o += blockDim.x) {
    int e = o & 7, lane = (o >> 3) & 63, nt = (o >> 9) & 7, ks = o >> 12;
    int k = ks * 32 + (lane >> 4) * 8 + e;
    int c = (lane & 15) + nt * 16;
    out[o] = f2bf(W[k * DD + c]);
  }
}

// LDS-staged multisplit: bucket edges by row>>BSHIFT into per-bucket spans of recs.
// rec = (col<<16 | fp16(val), row). Writes are contiguous per (tile,bucket) group.
__global__ __launch_bounds__(512) void multisplit(const int* __restrict__ rows,
                                                  const int* __restrict__ cols,
                                                  const float* __restrict__ vals,
                                                  int* __restrict__ cursor,
                                                  uint2* __restrict__ recs,
                                                  int E, int NB, int cap) {
  __shared__ u32 hist[512];
  __shared__ u32 scan_tmp[512];
  __shared__ u32 hbase[512];
  __shared__ int gbase[512];
  __shared__ u32 rankc[512];
  __shared__ uint2 stage[MS_TILE];
  const int t = threadIdx.x;
  const int tile0 = blockIdx.x * MS_TILE;
  hist[t] = 0;
  rankc[t] = 0;
  __syncthreads();
  int myb[MS_EPT];
  u32 mycv[MS_EPT], myrow[MS_EPT];
#pragma unroll
  for (int j = 0; j < MS_EPT; ++j) {
    int e = tile0 + j * 512 + t;
    if (e < E) {
      int r = rows[e];
      int b = r >> BSHIFT;
      myb[j] = b;
      myrow[j] = (u32)r;
      _Float16 hf = (_Float16)vals[e];
      mycv[j] = ((u32)cols[e] << 16) | (u32)__builtin_bit_cast(u16, hf);
      atomicAdd(&hist[b], 1u);
    } else {
      myb[j] = -1;
    }
  }
  __syncthreads();
  // exclusive scan of hist over 512 bins
  u32 v = hist[t];
  scan_tmp[t] = v;
  __syncthreads();
  for (int o = 1; o < 512; o <<= 1) {
    u32 x = (t >= o) ? scan_tmp[t - o] : 0;
    __syncthreads();
    scan_tmp[t] += x;
    __syncthreads();
  }
  hbase[t] = scan_tmp[t] - v;
  if (t < NB && v > 0) gbase[t] = atomicAdd(&cursor[t], (int)v);
  __syncthreads();
  // rank within (tile,bucket) and stage in bucket-sorted order
#pragma unroll
  for (int j = 0; j < MS_EPT; ++j) {
    if (myb[j] >= 0) {
      u32 rk = atomicAdd(&rankc[myb[j]], 1u);
      stage[hbase[myb[j]] + rk].x = mycv[j];
      stage[hbase[myb[j]] + rk].y = myrow[j];
    }
  }
  __syncthreads();
  int cnt = E - tile0;
  cnt = cnt < MS_TILE ? cnt : MS_TILE;
  for (int k = t; k < cnt; k += 512) {
    uint2 rec = stage[k];
    int b = (int)(rec.y >> BSHIFT);
    int off = gbase[b] + (k - (int)hbase[b]);
    if (off < cap) recs[(size_t)b * cap + off] = rec;
  }
}

// Per-bucket CSR: row-sort the bucket's records in LDS, write coalesced 4B records
// plus per-row start/count. One block per bucket.
__global__ __launch_bounds__(512) void bucket_csr(const uint2* __restrict__ recs,
                                                  const int* __restrict__ cursor,
                                                  u32* __restrict__ recs2,
                                                  int* __restrict__ rowstart,
                                                  int* __restrict__ rowcnt, int n, int cap) {
  __shared__ int hist[BROWS];
  __shared__ int sc[BROWS];
  __shared__ int hbase[BROWS];
  __shared__ u32 rank[BROWS];
  __shared__ u32 stage[STAGE_CAP];
  const int t = threadIdx.x;
  const int b = blockIdx.x;
  int cnt = cursor[b];
  cnt = cnt < cap ? cnt : cap;
  const uint2* rb = recs + (size_t)b * cap;
  if (t < BROWS) { hist[t] = 0; rank[t] = 0; }
  __syncthreads();
  for (int i = t; i < cnt; i += 512) atomicAdd(&hist[rb[i].y & (BROWS - 1)], 1);
  __syncthreads();
  // exclusive scan over 128 bins
  if (t < BROWS) sc[t] = hist[t];
  __syncthreads();
  for (int o = 1; o < BROWS; o <<= 1) {
    int x = (t >= o && t < BROWS) ? sc[t - o] : 0;
    __syncthreads();
    if (t < BROWS) sc[t] += x;
    __syncthreads();
  }
  if (t < BROWS) {
    hbase[t] = sc[t] - hist[t];
    int r = (b << BSHIFT) + t;
    if (r < n) {
      rowstart[r] = b * cap + hbase[t];
      rowcnt[r] = hist[t];
    }
  }
  __syncthreads();
  for (int i = t; i < cnt; i += 512) {
    uint2 rec = rb[i];
    int lr = (int)(rec.y & (BROWS - 1));
    u32 p = atomicAdd(&rank[lr], 1u);
    stage[hbase[lr] + p] = rec.x;
  }
  __syncthreads();
  u32* ob = recs2 + (size_t)b * cap;
  for (int i = t; i < cnt; i += 512) ob[i] = stage[i];
}

// one wave per row; lane handles 2 consecutive d's (one 256B row per gather);
// register accumulation, no shfl/LDS in the gather loop.
__global__ void spmm_agg(const int* __restrict__ rowstart, const int* __restrict__ rowcnt,
                         const u32* __restrict__ recs2, const u16* __restrict__ xb,
                         u16* __restrict__ aggb, int n) {
  int row = blockIdx.x * 4 + (threadIdx.x >> 6);
  int lane = threadIdx.x & 63;
  if (row >= n) return;
  int s = rowstart[row];
  int e2 = s + rowcnt[row];
  float a0 = 0.f, a1 = 0.f;
  int j = s;
  for (; j + 3 < e2; j += 4) {
    u32 pk0 = recs2[j], pk1 = recs2[j + 1], pk2 = recs2[j + 2], pk3 = recs2[j + 3];
    u32 x0 = *reinterpret_cast<const u32*>(xb + (size_t)(pk0 >> 16) * DD + lane * 2);
    u32 x1 = *reinterpret_cast<const u32*>(xb + (size_t)(pk1 >> 16) * DD + lane * 2);
    u32 x2 = *reinterpret_cast<const u32*>(xb + (size_t)(pk2 >> 16) * DD + lane * 2);
    u32 x3 = *reinterpret_cast<const u32*>(xb + (size_t)(pk3 >> 16) * DD + lane * 2);
    float v0 = f16val(pk0), v1 = f16val(pk1), v2 = f16val(pk2), v3 = f16val(pk3);
    a0 += v0 * bf2f((u16)(x0 & 0xffff)) + v1 * bf2f((u16)(x1 & 0xffff)) +
          v2 * bf2f((u16)(x2 & 0xffff)) + v3 * bf2f((u16)(x3 & 0xffff));
    a1 += v0 * bf2f((u16)(x0 >> 16)) + v1 * bf2f((u16)(x1 >> 16)) +
          v2 * bf2f((u16)(x2 >> 16)) + v3 * bf2f((u16)(x3 >> 16));
  }
  for (; j < e2; ++j) {
    u32 pk = recs2[j];
    u32 x0 = *reinterpret_cast<const u32*>(xb + (size_t)(pk >> 16) * DD + lane * 2);
    float v0 = f16val(pk);
    a0 += v0 * bf2f((u16)(x0 & 0xffff));
    a1 += v0 * bf2f((u16)(x0 >> 16));
  }
  u32 o = ((u32)f2bf(a1) << 16) | (u32)f2bf(a0);
  *reinterpret_cast<u32*>(aggb + (size_t)row * DD + lane * 2) = o;
}

// Fused 2-layer MLP: out = (relu(A@W1+b1))@W2 + b2, bf16 out.
// ASRC 0: A is fp32; ASRC 1: A is bf16. Per-wave private LDS tile for h1.
template <int ASRC>
__global__ __launch_bounds__(256) void mlp_fused(const void* __restrict__ Ain,
                                                 const u16* __restrict__ W1p,
                                                 const float* __restrict__ b1,
                                                 const u16* __restrict__ W2p,
                                                 const float* __restrict__ b2,
                                                 u16* __restrict__ outB, int n) {
  __shared__ u16 sm[4][32][136];
  const int lane = threadIdx.x & 63;
  const int wid = threadIdx.x >> 6;
  const int row0 = blockIdx.x * 128 + wid * 32;
  const int ar = lane & 15, ak = (lane >> 4) * 8;
  const int crow = 4 * (lane >> 4), ccol = lane & 15;

  f32x4 acc[2][8];
#pragma unroll
  for (int m = 0; m < 2; ++m)
#pragma unroll
    for (int t = 0; t < 8; ++t) acc[m][t] = f32x4{0.f, 0.f, 0.f, 0.f};

#pragma unroll
  for (int ks = 0; ks < 4; ++ks) {
    short8 a[2];
#pragma unroll
    for (int m = 0; m < 2; ++m) {
      int r = row0 + m * 16 + ar;
      r = r < n ? r : n - 1;
      if (ASRC == 0) {
        const float* Ap = (const float*)Ain + (size_t)r * DD + ks * 32 + ak;
        float4 f0 = *reinterpret_cast<const float4*>(Ap);
        float4 f1 = *reinterpret_cast<const float4*>(Ap + 4);
        short8 tv;
        tv[0] = (short)f2bf(f0.x); tv[1] = (short)f2bf(f0.y);
        tv[2] = (short)f2bf(f0.z); tv[3] = (short)f2bf(f0.w);
        tv[4] = (short)f2bf(f1.x); tv[5] = (short)f2bf(f1.y);
        tv[6] = (short)f2bf(f1.z); tv[7] = (short)f2bf(f1.w);
        a[m] = tv;
      } else {
        a[m] = *reinterpret_cast<const short8*>((const u16*)Ain + (size_t)r * DD + ks * 32 + ak);
      }
    }
#pragma unroll
    for (int nt = 0; nt < 8; ++nt) {
      short8 bfr = *reinterpret_cast<const short8*>(W1p + (((ks * 8 + nt) * 64 + lane) * 8));
#pragma unroll
      for (int m = 0; m < 2; ++m)
        acc[m][nt] = __builtin_amdgcn_mfma_f32_16x16x32_bf16(a[m], bfr, acc[m][nt], 0, 0, 0);
    }
  }
#pragma unroll
  for (int m = 0; m < 2; ++m)
#pragma unroll
    for (int nt = 0; nt < 8; ++nt) {
      float bsv = b1[ccol + nt * 16];
#pragma unroll
      for (int e = 0; e < 4; ++e) {
        float v = acc[m][nt][e] + bsv;
        v = v > 0.f ? v : 0.f;
        sm[wid][m * 16 + crow + e][ccol + nt * 16] = f2bf(v);
      }
    }
  __syncthreads();

  f32x4 acc2[2][8];
#pragma unroll
  for (int m = 0; m < 2; ++m)
#pragma unroll
    for (int t = 0; t < 8; ++t) acc2[m][t] = f32x4{0.f, 0.f, 0.f, 0.f};
#pragma unroll
  for (int ks = 0; ks < 4; ++ks) {
    short8 a2[2];
#pragma unroll
    for (int m = 0; m < 2; ++m)
      a2[m] = *reinterpret_cast<const short8*>(&sm[wid][m * 16 + ar][ks * 32 + ak]);
#pragma unroll
    for (int nt = 0; nt < 8; ++nt) {
      short8 bfr = *reinterpret_cast<const short8*>(W2p + (((ks * 8 + nt) * 64 + lane) * 8));
#pragma unroll
      for (int m = 0; m < 2; ++m)
        acc2[m][nt] = __builtin_amdgcn_mfma_f32_16x16x32_bf16(a2[m], bfr, acc2[m][nt], 0, 0, 0);
    }
  }
#pragma unroll
  for (int m = 0; m < 2; ++m)
#pragma unroll
    for (int nt = 0; nt < 8; ++nt) {
      int col = ccol + nt * 16;
      float bsv = b2[col];
#pragma unroll
      for (int e = 0; e < 4; ++e) {
        int r = row0 + m * 16 + crow + e;
        if (r < n) outB[(size_t)r * DD + col] = f2bf(acc2[m][nt][e] + bsv);
      }
    }
}

// Fully fused gates + final:
//   z  = sig(out@Wu1 + x@Wu2 + bu1+bu2)
//   r  = sig(out@Wr1 + x@Wr2 + br1+br2)
//   oi = (out@Wo1 + bo1) + (r*x)@Wo2 + bo2   (rx via wave-private LDS tile)
//   result = (1-z)*x + z*tanh(oi)   -> fp32 d_out
__global__ __launch_bounds__(256) void gates_final(
    const u16* __restrict__ Ao, const u16* __restrict__ Ax, const u16* __restrict__ Wu1p,
    const u16* __restrict__ Wu2p, const u16* __restrict__ Wr1p, const u16* __restrict__ Wr2p,
    const u16* __restrict__ Wo1p, const u16* __restrict__ Wo2p, const float* __restrict__ bu1,
    const float* __restrict__ bu2, const float* __restrict__ br1, const float* __restrict__ br2,
    const float* __restrict__ bo1, const float* __restrict__ bo2, float* __restrict__ out,
    int n) {
  __shared__ u16 sm[4][16][136];
  const int lane = threadIdx.x & 63;
  const int wid = threadIdx.x >> 6;
  const int row0 = blockIdx.x * 64 + wid * 16;
  const int ar = lane & 15, ak = (lane >> 4) * 8;
  const int crow = 4 * (lane >> 4), ccol = lane & 15;

  f32x4 aZ[8], aR[8], aO[8];
#pragma unroll
  for (int t = 0; t < 8; ++t) {
    aZ[t] = f32x4{0.f, 0.f, 0.f, 0.f};
    aR[t] = f32x4{0.f, 0.f, 0.f, 0.f};
    aO[t] = f32x4{0.f, 0.f, 0.f, 0.f};
  }
#pragma unroll
  for (int ks = 0; ks < 4; ++ks) {
    int r = row0 + ar;
    r = r < n ? r : n - 1;
    short8 ao = *reinterpret_cast<const short8*>(Ao + (size_t)r * DD + ks * 32 + ak);
    short8 ax = *reinterpret_cast<const short8*>(Ax + (size_t)r * DD + ks * 32 + ak);
#pragma unroll
    for (int nt = 0; nt < 8; ++nt) {
      size_t bo = (size_t)(((ks * 8 + nt) * 64 + lane) * 8);
      short8 b1 = *reinterpret_cast<const short8*>(Wu1p + bo);
      short8 b2 = *reinterpret_cast<const short8*>(Wu2p + bo);
      short8 b3 = *reinterpret_cast<const short8*>(Wr1p + bo);
      short8 b4 = *reinterpret_cast<const short8*>(Wr2p + bo);
      short8 b5 = *reinterpret_cast<const short8*>(Wo1p + bo);
      aZ[nt] = __builtin_amdgcn_mfma_f32_16x16x32_bf16(ao, b1, aZ[nt], 0, 0, 0);
      aZ[nt] = __builtin_amdgcn_mfma_f32_16x16x32_bf16(ax, b2, aZ[nt], 0, 0, 0);
      aR[nt] = __builtin_amdgcn_mfma_f32_16x16x32_bf16(ao, b3, aR[nt], 0, 0, 0);
      aR[nt] = __builtin_amdgcn_mfma_f32_16x16x32_bf16(ax, b4, aR[nt], 0, 0, 0);
      aO[nt] = __builtin_amdgcn_mfma_f32_16x16x32_bf16(ao, b5, aO[nt], 0, 0, 0);
    }
  }
  // epilogue 1: z (keep f32 in aZ), oi1 (fold bias into aO), rx -> LDS
#pragma unroll
  for (int nt = 0; nt < 8; ++nt) {
    int col = ccol + nt * 16;
    float bz = bu1[col] + bu2[col];
    float br_ = br1[col] + br2[col];
    float bo_ = bo1[col];
#pragma unroll
    for (int e = 0; e < 4; ++e) {
      int r = row0 + crow + e;
      float z = sigmoidf_(aZ[nt][e] + bz);
      float rr = sigmoidf_(aR[nt][e] + br_);
      aZ[nt][e] = z;
      aO[nt][e] = aO[nt][e] + bo_;
      float xv = 0.f;
      if (r < n) xv = bf2f(Ax[(size_t)r * DD + col]);
      sm[wid][crow + e][col] = f2bf(rr * xv);
    }
  }
  __syncthreads();

  // GEMM2: rx@Wo2 from LDS (wave-private tile)
  f32x4 acc2[8];
#pragma unroll
  for (int t = 0; t < 8; ++t) acc2[t] = f32x4{0.f, 0.f, 0.f, 0.f};
#pragma unroll
  for (int ks = 0; ks < 4; ++ks) {
    short8 a2 = *reinterpret_cast<const short8*>(&sm[wid][ar][ks * 32 + ak]);
#pragma unroll
    for (int nt = 0; nt < 8; ++nt) {
      short8 bfr = *reinterpret_cast<const short8*>(Wo2p + (((ks * 8 + nt) * 64 + lane) * 8));
      acc2[nt] = __builtin_amdgcn_mfma_f32_16x16x32_bf16(a2, bfr, acc2[nt], 0, 0, 0);
    }
  }
  // final epilogue: h = tanh(oi1 + rx@Wo2 + bo2); out = (1-z)*x + z*h
#pragma unroll
  for (int nt = 0; nt < 8; ++nt) {
    int col = ccol + nt * 16;
    float bo2v = bo2[col];
#pragma unroll
    for (int e = 0; e < 4; ++e) {
      int r = row0 + crow + e;
      if (r < n) {
        size_t idx = (size_t)r * DD + col;
        float oi = acc2[nt][e] + bo2v + aO[nt][e];
        float h = tanhf_(oi);
        float z = aZ[nt][e];
        float xv = bf2f(Ax[idx]);
        out[idx] = (1.f - z) * xv + z * h;
      }
    }
  }
}

extern "C" void kernel_launch(void* const* d_in, const int* in_sizes, int n_in,
                              void* d_out, int out_size, void* d_ws, size_t ws_size,
                              hipStream_t stream) {
  const int n = in_sizes[0] / DD;  // 50000
  const int E = in_sizes[1];       // 1.6M
  const float* x_in = (const float*)d_in[0];
  const int* rows = (const int*)d_in[1];
  const int* cols = (const int*)d_in[2];
  const float* vals = (const float*)d_in[3];
  const float* Wm[10];
  const float* Bm[10];
  for (int i = 0; i < 10; ++i) {
    Wm[i] = (const float*)d_in[4 + 2 * i];
    Bm[i] = (const float*)d_in[5 + 2 * i];
  }

  const int NB = (n + BROWS - 1) >> BSHIFT;           // 391
  int cap = (((E / NB) * 5) / 4 + 511) & ~511;        // ~5120, 16-sigma slack
  cap = cap < STAGE_CAP ? cap : STAGE_CAP;

  char* base = (char*)d_ws;
  size_t off = 0;
  auto alloc = [&](size_t bytes) -> char* {
    char* p = base + off;
    off += (bytes + 255) & ~(size_t)255;
    return p;
  };
  u16* wpack = (u16*)alloc((size_t)10 * 16384 * 2);
  u16* x_b = (u16*)alloc((size_t)n * DD * 2);
  u16* agg_b = (u16*)alloc((size_t)n * DD * 2);  // reused as out_b
  int* cursor = (int*)alloc((size_t)NB * 4);
  int* rowstart = (int*)alloc((size_t)n * 4);
  int* rowcnt = (int*)alloc((size_t)n * 4);
  uint2* recs = (uint2*)alloc((size_t)NB * cap * 8);
  u32* recs2 = (u32*)alloc((size_t)NB * cap * 4);
  (void)ws_size;
  (void)n_in;
  (void)out_size;

  hipMemsetAsync(cursor, 0, (size_t)NB * 4, stream);
  WPtrs wp;
  for (int i = 0; i < 10; ++i) wp.w[i] = Wm[i];
  pack_weights<<<10, 256, 0, stream>>>(wp, wpack);
  // bucket the edges (coalesced writes)
  multisplit<<<(E + MS_TILE - 1) / MS_TILE, 512, 0, stream>>>(rows, cols, vals, cursor, recs, E,
                                                             NB, cap);
  // row-sort each bucket in LDS -> per-row CSR with coalesced writes
  bucket_csr<<<NB, 512, 0, stream>>>(recs, cursor, recs2, rowstart, rowcnt, n, cap);
  int gblocks = (n + 127) / 128;
  // x = mlp2(x_in, m1_*)  (fp32 input, fused 2-layer)
  mlp_fused<0><<<gblocks, 256, 0, stream>>>(x_in, wpack + 0 * 16384, Bm[0], wpack + 1 * 16384,
                                            Bm[1], x_b, n);
  // agg = segment_sum(vals * x[cols], rows)  (wave-per-row, register accum)
  spmm_agg<<<(n + 3) / 4, 256, 0, stream>>>(rowstart, rowcnt, recs2, x_b, agg_b, n);
  // out = mlp2(agg, m2_*)  (bf16 input, fused 2-layer)
  mlp_fused<1><<<gblocks, 256, 0, stream>>>(agg_b, wpack + 2 * 16384, Bm[2], wpack + 3 * 16384,
                                            Bm[3], agg_b, n);
  // gates + final fused (writes fp32 d_out directly)
  gates_final<<<(n + 63) / 64, 256, 0, stream>>>(
      agg_b, x_b, wpack + 4 * 16384, wpack + 5 * 16384, wpack + 6 * 16384, wpack + 7 * 16384,
      wpack + 8 * 16384, wpack + 9 * 16384, Bm[4], Bm[5], Bm[6], Bm[7], Bm[8], Bm[9],
      (float*)d_out, n);
}

// Round 9
// 306.129 us; speedup vs baseline: 5.5357x; 1.1666x over previous
//
#include <hip/hip_runtime.h>

#define DD 128
#define BSHIFT 7
#define BROWS 128
#define MS_TILE 4096
#define MS_EPT 8       // edges per thread at 512 threads
#define STAGE_CAP 6144 // bucket_csr LDS stage capacity (>= cap)

typedef __attribute__((ext_vector_type(8))) short short8;
typedef __attribute__((ext_vector_type(4))) float f32x4;
typedef unsigned short u16;
typedef unsigned int u32;

__device__ __forceinline__ u16 f2bf(float f) {
  u32 u = __builtin_bit_cast(u32, f);
  u += 0x7fffu + ((u >> 16) & 1u);
  return (u16)(u >> 16);
}
__device__ __forceinline__ float bf2f(u16 s) {
  u32 u = ((u32)s) << 16;
  return __builtin_bit_cast(float, u);
}
__device__ __forceinline__ float f16val(u32 cv) {
  return (float)__builtin_bit_cast(_Float16, (u16)(cv & 0xffffu));
}
__device__ __forceinline__ float sigmoidf_(float v) { return 1.f / (1.f + __expf(-v)); }
__device__ __forceinline__ float tanhf_(float v) {
  float e = __expf(-2.f * v);
  return (1.f - e) / (1.f + e);
}

struct WPtrs { const float* w[10]; };

// Pack W [k][n] (row-major fp32, 128x128) into fragment-major bf16:
// Bp[((ks*8+nt)*64 + lane)*8 + e] = bf16( W[ks*32 + (lane>>4)*8 + e][(lane&15) + nt*16] )
__global__ void pack_weights(WPtrs wp, u16* __restrict__ bp) {
  const float* W = wp.w[blockIdx.x];
  u16* out = bp + (size_t)blockIdx.x * 16384;
  for (int o = threadIdx.x; o < 16384; o += blockDim.x) {
    int e = o & 7, lane = (o >> 3) & 63, nt = (o >> 9) & 7, ks = o >> 12;
    int k = ks * 32 + (lane >> 4) * 8 + e;
    int c = (lane & 15) + nt * 16;
    out[o] = f2bf(W[k * DD + c]);
  }
}

// LDS-staged multisplit: bucket edges by row>>BSHIFT into per-bucket spans of recs.
// rec = (col<<16 | fp16(val), row). Writes are contiguous per (tile,bucket) group.
__global__ __launch_bounds__(512) void multisplit(const int* __restrict__ rows,
                                                  const int* __restrict__ cols,
                                                  const float* __restrict__ vals,
                                                  int* __restrict__ cursor,
                                                  uint2* __restrict__ recs,
                                                  int E, int NB, int cap) {
  __shared__ u32 hist[512];
  __shared__ u32 scan_tmp[512];
  __shared__ u32 hbase[512];
  __shared__ int gbase[512];
  __shared__ u32 rankc[512];
  __shared__ uint2 stage[MS_TILE];
  const int t = threadIdx.x;
  const int tile0 = blockIdx.x * MS_TILE;
  hist[t] = 0;
  rankc[t] = 0;
  __syncthreads();
  int myb[MS_EPT];
  u32 mycv[MS_EPT], myrow[MS_EPT];
#pragma unroll
  for (int j = 0; j < MS_EPT; ++j) {
    int e = tile0 + j * 512 + t;
    if (e < E) {
      int r = rows[e];
      int b = r >> BSHIFT;
      myb[j] = b;
      myrow[j] = (u32)r;
      _Float16 hf = (_Float16)vals[e];
      mycv[j] = ((u32)cols[e] << 16) | (u32)__builtin_bit_cast(u16, hf);
      atomicAdd(&hist[b], 1u);
    } else {
      myb[j] = -1;
    }
  }
  __syncthreads();
  // exclusive scan of hist over 512 bins
  u32 v = hist[t];
  scan_tmp[t] = v;
  __syncthreads();
  for (int o = 1; o < 512; o <<= 1) {
    u32 x = (t >= o) ? scan_tmp[t - o] : 0;
    __syncthreads();
    scan_tmp[t] += x;
    __syncthreads();
  }
  hbase[t] = scan_tmp[t] - v;
  if (t < NB && v > 0) gbase[t] = atomicAdd(&cursor[t], (int)v);
  __syncthreads();
  // rank within (tile,bucket) and stage in bucket-sorted order
#pragma unroll
  for (int j = 0; j < MS_EPT; ++j) {
    if (myb[j] >= 0) {
      u32 rk = atomicAdd(&rankc[myb[j]], 1u);
      stage[hbase[myb[j]] + rk].x = mycv[j];
      stage[hbase[myb[j]] + rk].y = myrow[j];
    }
  }
  __syncthreads();
  int cnt = E - tile0;
  cnt = cnt < MS_TILE ? cnt : MS_TILE;
  for (int k = t; k < cnt; k += 512) {
    uint2 rec = stage[k];
    int b = (int)(rec.y >> BSHIFT);
    int off = gbase[b] + (k - (int)hbase[b]);
    if (off < cap) recs[(size_t)b * cap + off] = rec;
  }
}

// Per-bucket CSR: row-sort the bucket's records in LDS, write coalesced 4B records
// plus per-row start/count. One block per bucket.
__global__ __launch_bounds__(512) void bucket_csr(const uint2* __restrict__ recs,
                                                  const int* __restrict__ cursor,
                                                  u32* __restrict__ recs2,
                                                  int* __restrict__ rowstart,
                                                  int* __restrict__ rowcnt, int n, int cap) {
  __shared__ int hist[BROWS];
  __shared__ int sc[BROWS];
  __shared__ int hbase[BROWS];
  __shared__ u32 rank[BROWS];
  __shared__ u32 stage[STAGE_CAP];
  const int t = threadIdx.x;
  const int b = blockIdx.x;
  int cnt = cursor[b];
  cnt = cnt < cap ? cnt : cap;
  const uint2* rb = recs + (size_t)b * cap;
  if (t < BROWS) { hist[t] = 0; rank[t] = 0; }
  __syncthreads();
  for (int i = t; i < cnt; i += 512) atomicAdd(&hist[rb[i].y & (BROWS - 1)], 1);
  __syncthreads();
  // exclusive scan over 128 bins
  if (t < BROWS) sc[t] = hist[t];
  __syncthreads();
  for (int o = 1; o < BROWS; o <<= 1) {
    int x = (t >= o && t < BROWS) ? sc[t - o] : 0;
    __syncthreads();
    if (t < BROWS) sc[t] += x;
    __syncthreads();
  }
  if (t < BROWS) {
    hbase[t] = sc[t] - hist[t];
    int r = (b << BSHIFT) + t;
    if (r < n) {
      rowstart[r] = b * cap + hbase[t];
      rowcnt[r] = hist[t];
    }
  }
  __syncthreads();
  for (int i = t; i < cnt; i += 512) {
    uint2 rec = rb[i];
    int lr = (int)(rec.y & (BROWS - 1));
    u32 p = atomicAdd(&rank[lr], 1u);
    stage[hbase[lr] + p] = rec.x;
  }
  __syncthreads();
  u32* ob = recs2 + (size_t)b * cap;
  for (int i = t; i < cnt; i += 512) ob[i] = stage[i];
}

// one wave per row; lane handles 2 consecutive d's (one 256B row per gather);
// register accumulation, no shfl/LDS in the gather loop.
__global__ void spmm_agg(const int* __restrict__ rowstart, const int* __restrict__ rowcnt,
                         const u32* __restrict__ recs2, const u16* __restrict__ xb,
                         u16* __restrict__ aggb, int n) {
  int row = blockIdx.x * 4 + (threadIdx.x >> 6);
  int lane = threadIdx.x & 63;
  if (row >= n) return;
  int s = rowstart[row];
  int e2 = s + rowcnt[row];
  float a0 = 0.f, a1 = 0.f;
  int j = s;
  for (; j + 3 < e2; j += 4) {
    u32 pk0 = recs2[j], pk1 = recs2[j + 1], pk2 = recs2[j + 2], pk3 = recs2[j + 3];
    u32 x0 = *reinterpret_cast<const u32*>(xb + (size_t)(pk0 >> 16) * DD + lane * 2);
    u32 x1 = *reinterpret_cast<const u32*>(xb + (size_t)(pk1 >> 16) * DD + lane * 2);
    u32 x2 = *reinterpret_cast<const u32*>(xb + (size_t)(pk2 >> 16) * DD + lane * 2);
    u32 x3 = *reinterpret_cast<const u32*>(xb + (size_t)(pk3 >> 16) * DD + lane * 2);
    float v0 = f16val(pk0), v1 = f16val(pk1), v2 = f16val(pk2), v3 = f16val(pk3);
    a0 += v0 * bf2f((u16)(x0 & 0xffff)) + v1 * bf2f((u16)(x1 & 0xffff)) +
          v2 * bf2f((u16)(x2 & 0xffff)) + v3 * bf2f((u16)(x3 & 0xffff));
    a1 += v0 * bf2f((u16)(x0 >> 16)) + v1 * bf2f((u16)(x1 >> 16)) +
          v2 * bf2f((u16)(x2 >> 16)) + v3 * bf2f((u16)(x3 >> 16));
  }
  for (; j < e2; ++j) {
    u32 pk = recs2[j];
    u32 x0 = *reinterpret_cast<const u32*>(xb + (size_t)(pk >> 16) * DD + lane * 2);
    float v0 = f16val(pk);
    a0 += v0 * bf2f((u16)(x0 & 0xffff));
    a1 += v0 * bf2f((u16)(x0 >> 16));
  }
  u32 o = ((u32)f2bf(a1) << 16) | (u32)f2bf(a0);
  *reinterpret_cast<u32*>(aggb + (size_t)row * DD + lane * 2) = o;
}

// Fused 2-layer MLP, column-split: block = 32 rows, 4 waves as (m,c) =
// (row-tile, col-half). Each wave: 16 rows x 64 cols. Grid = n/32 blocks
// (4x the waves of the old 128-row version -> latency hiding).
// ASRC 0: A is fp32; ASRC 1: A is bf16.
template <int ASRC>
__global__ __launch_bounds__(256) void mlp_fused(const void* __restrict__ Ain,
                                                 const u16* __restrict__ W1p,
                                                 const float* __restrict__ b1,
                                                 const u16* __restrict__ W2p,
                                                 const float* __restrict__ b2,
                                                 u16* __restrict__ outB, int n) {
  __shared__ u16 sm[32][136];
  const int lane = threadIdx.x & 63;
  const int wid = threadIdx.x >> 6;
  const int m = wid >> 1, c = wid & 1;
  const int row0 = blockIdx.x * 32 + m * 16;
  const int ar = lane & 15, ak = (lane >> 4) * 8;
  const int crow = 4 * (lane >> 4), ccol = lane & 15;

  f32x4 acc[4];
#pragma unroll
  for (int t = 0; t < 4; ++t) acc[t] = f32x4{0.f, 0.f, 0.f, 0.f};

#pragma unroll
  for (int ks = 0; ks < 4; ++ks) {
    short8 a;
    int r = row0 + ar;
    r = r < n ? r : n - 1;
    if (ASRC == 0) {
      const float* Ap = (const float*)Ain + (size_t)r * DD + ks * 32 + ak;
      float4 f0 = *reinterpret_cast<const float4*>(Ap);
      float4 f1 = *reinterpret_cast<const float4*>(Ap + 4);
      short8 tv;
      tv[0] = (short)f2bf(f0.x); tv[1] = (short)f2bf(f0.y);
      tv[2] = (short)f2bf(f0.z); tv[3] = (short)f2bf(f0.w);
      tv[4] = (short)f2bf(f1.x); tv[5] = (short)f2bf(f1.y);
      tv[6] = (short)f2bf(f1.z); tv[7] = (short)f2bf(f1.w);
      a = tv;
    } else {
      a = *reinterpret_cast<const short8*>((const u16*)Ain + (size_t)r * DD + ks * 32 + ak);
    }
#pragma unroll
    for (int nt4 = 0; nt4 < 4; ++nt4) {
      int nt = c * 4 + nt4;
      short8 bfr = *reinterpret_cast<const short8*>(W1p + (((ks * 8 + nt) * 64 + lane) * 8));
      acc[nt4] = __builtin_amdgcn_mfma_f32_16x16x32_bf16(a, bfr, acc[nt4], 0, 0, 0);
    }
  }
  // epilogue 1: bias + relu -> LDS (block tile, wave-disjoint quadrant)
#pragma unroll
  for (int nt4 = 0; nt4 < 4; ++nt4) {
    int col = (c * 4 + nt4) * 16 + ccol;
    float bsv = b1[col];
#pragma unroll
    for (int e = 0; e < 4; ++e) {
      float v = acc[nt4][e] + bsv;
      v = v > 0.f ? v : 0.f;
      sm[m * 16 + crow + e][col] = f2bf(v);
    }
  }
  __syncthreads();

  // GEMM2 from LDS (full K = 128 across both col-halves)
  f32x4 acc2[4];
#pragma unroll
  for (int t = 0; t < 4; ++t) acc2[t] = f32x4{0.f, 0.f, 0.f, 0.f};
#pragma unroll
  for (int ks = 0; ks < 4; ++ks) {
    short8 a2 = *reinterpret_cast<const short8*>(&sm[m * 16 + ar][ks * 32 + ak]);
#pragma unroll
    for (int nt4 = 0; nt4 < 4; ++nt4) {
      int nt = c * 4 + nt4;
      short8 bfr = *reinterpret_cast<const short8*>(W2p + (((ks * 8 + nt) * 64 + lane) * 8));
      acc2[nt4] = __builtin_amdgcn_mfma_f32_16x16x32_bf16(a2, bfr, acc2[nt4], 0, 0, 0);
    }
  }
#pragma unroll
  for (int nt4 = 0; nt4 < 4; ++nt4) {
    int col = (c * 4 + nt4) * 16 + ccol;
    float bsv = b2[col];
#pragma unroll
    for (int e = 0; e < 4; ++e) {
      int r = row0 + crow + e;
      if (r < n) outB[(size_t)r * DD + col] = f2bf(acc2[nt4][e] + bsv);
    }
  }
}

// Fully fused gates + final, column-split like mlp_fused (32-row blocks):
//   z  = sig(out@Wu1 + x@Wu2 + bu1+bu2)
//   r  = sig(out@Wr1 + x@Wr2 + br1+br2)
//   oi = (out@Wo1 + bo1) + (r*x)@Wo2 + bo2   (rx via block LDS tile)
//   result = (1-z)*x + z*tanh(oi)   -> fp32 d_out
__global__ __launch_bounds__(256) void gates_final(
    const u16* __restrict__ Ao, const u16* __restrict__ Ax, const u16* __restrict__ Wu1p,
    const u16* __restrict__ Wu2p, const u16* __restrict__ Wr1p, const u16* __restrict__ Wr2p,
    const u16* __restrict__ Wo1p, const u16* __restrict__ Wo2p, const float* __restrict__ bu1,
    const float* __restrict__ bu2, const float* __restrict__ br1, const float* __restrict__ br2,
    const float* __restrict__ bo1, const float* __restrict__ bo2, float* __restrict__ out,
    int n) {
  __shared__ u16 sm[32][136];
  const int lane = threadIdx.x & 63;
  const int wid = threadIdx.x >> 6;
  const int m = wid >> 1, c = wid & 1;
  const int row0 = blockIdx.x * 32 + m * 16;
  const int ar = lane & 15, ak = (lane >> 4) * 8;
  const int crow = 4 * (lane >> 4), ccol = lane & 15;

  f32x4 aZ[4], aR[4], aO[4];
#pragma unroll
  for (int t = 0; t < 4; ++t) {
    aZ[t] = f32x4{0.f, 0.f, 0.f, 0.f};
    aR[t] = f32x4{0.f, 0.f, 0.f, 0.f};
    aO[t] = f32x4{0.f, 0.f, 0.f, 0.f};
  }
#pragma unroll
  for (int ks = 0; ks < 4; ++ks) {
    int r = row0 + ar;
    r = r < n ? r : n - 1;
    short8 ao = *reinterpret_cast<const short8*>(Ao + (size_t)r * DD + ks * 32 + ak);
    short8 ax = *reinterpret_cast<const short8*>(Ax + (size_t)r * DD + ks * 32 + ak);
#pragma unroll
    for (int nt4 = 0; nt4 < 4; ++nt4) {
      int nt = c * 4 + nt4;
      size_t bo = (size_t)(((ks * 8 + nt) * 64 + lane) * 8);
      short8 b1 = *reinterpret_cast<const short8*>(Wu1p + bo);
      short8 b2 = *reinterpret_cast<const short8*>(Wu2p + bo);
      short8 b3 = *reinterpret_cast<const short8*>(Wr1p + bo);
      short8 b4 = *reinterpret_cast<const short8*>(Wr2p + bo);
      short8 b5 = *reinterpret_cast<const short8*>(Wo1p + bo);
      aZ[nt4] = __builtin_amdgcn_mfma_f32_16x16x32_bf16(ao, b1, aZ[nt4], 0, 0, 0);
      aZ[nt4] = __builtin_amdgcn_mfma_f32_16x16x32_bf16(ax, b2, aZ[nt4], 0, 0, 0);
      aR[nt4] = __builtin_amdgcn_mfma_f32_16x16x32_bf16(ao, b3, aR[nt4], 0, 0, 0);
      aR[nt4] = __builtin_amdgcn_mfma_f32_16x16x32_bf16(ax, b4, aR[nt4], 0, 0, 0);
      aO[nt4] = __builtin_amdgcn_mfma_f32_16x16x32_bf16(ao, b5, aO[nt4], 0, 0, 0);
    }
  }
  // epilogue 1: z (keep f32 in aZ), oi1 (fold bias into aO), rx -> LDS
#pragma unroll
  for (int nt4 = 0; nt4 < 4; ++nt4) {
    int col = (c * 4 + nt4) * 16 + ccol;
    float bz = bu1[col] + bu2[col];
    float br_ = br1[col] + br2[col];
    float bo_ = bo1[col];
#pragma unroll
    for (int e = 0; e < 4; ++e) {
      int r = row0 + crow + e;
      float z = sigmoidf_(aZ[nt4][e] + bz);
      float rr = sigmoidf_(aR[nt4][e] + br_);
      aZ[nt4][e] = z;
      aO[nt4][e] = aO[nt4][e] + bo_;
      float xv = 0.f;
      if (r < n) xv = bf2f(Ax[(size_t)r * DD + col]);
      sm[m * 16 + crow + e][col] = f2bf(rr * xv);
    }
  }
  __syncthreads();

  // GEMM2: rx@Wo2 from LDS (full K across both col-halves)
  f32x4 acc2[4];
#pragma unroll
  for (int t = 0; t < 4; ++t) acc2[t] = f32x4{0.f, 0.f, 0.f, 0.f};
#pragma unroll
  for (int ks = 0; ks < 4; ++ks) {
    short8 a2 = *reinterpret_cast<const short8*>(&sm[m * 16 + ar][ks * 32 + ak]);
#pragma unroll
    for (int nt4 = 0; nt4 < 4; ++nt4) {
      int nt = c * 4 + nt4;
      short8 bfr = *reinterpret_cast<const short8*>(Wo2p + (((ks * 8 + nt) * 64 + lane) * 8));
      acc2[nt4] = __builtin_amdgcn_mfma_f32_16x16x32_bf16(a2, bfr, acc2[nt4], 0, 0, 0);
    }
  }
  // final epilogue: h = tanh(oi1 + rx@Wo2 + bo2); out = (1-z)*x + z*h
#pragma unroll
  for (int nt4 = 0; nt4 < 4; ++nt4) {
    int col = (c * 4 + nt4) * 16 + ccol;
    float bo2v = bo2[col];
#pragma unroll
    for (int e = 0; e < 4; ++e) {
      int r = row0 + crow + e;
      if (r < n) {
        size_t idx = (size_t)r * DD + col;
        float oi = acc2[nt4][e] + bo2v + aO[nt4][e];
        float h = tanhf_(oi);
        float z = aZ[nt4][e];
        float xv = bf2f(Ax[idx]);
        out[idx] = (1.f - z) * xv + z * h;
      }
    }
  }
}

extern "C" void kernel_launch(void* const* d_in, const int* in_sizes, int n_in,
                              void* d_out, int out_size, void* d_ws, size_t ws_size,
                              hipStream_t stream) {
  const int n = in_sizes[0] / DD;  // 50000
  const int E = in_sizes[1];       // 1.6M
  const float* x_in = (const float*)d_in[0];
  const int* rows = (const int*)d_in[1];
  const int* cols = (const int*)d_in[2];
  const float* vals = (const float*)d_in[3];
  const float* Wm[10];
  const float* Bm[10];
  for (int i = 0; i < 10; ++i) {
    Wm[i] = (const float*)d_in[4 + 2 * i];
    Bm[i] = (const float*)d_in[5 + 2 * i];
  }

  const int NB = (n + BROWS - 1) >> BSHIFT;           // 391
  int cap = (((E / NB) * 5) / 4 + 511) & ~511;        // ~5120, 16-sigma slack
  cap = cap < STAGE_CAP ? cap : STAGE_CAP;

  char* base = (char*)d_ws;
  size_t off = 0;
  auto alloc = [&](size_t bytes) -> char* {
    char* p = base + off;
    off += (bytes + 255) & ~(size_t)255;
    return p;
  };
  u16* wpack = (u16*)alloc((size_t)10 * 16384 * 2);
  u16* x_b = (u16*)alloc((size_t)n * DD * 2);
  u16* agg_b = (u16*)alloc((size_t)n * DD * 2);  // reused as out_b
  int* cursor = (int*)alloc((size_t)NB * 4);
  int* rowstart = (int*)alloc((size_t)n * 4);
  int* rowcnt = (int*)alloc((size_t)n * 4);
  uint2* recs = (uint2*)alloc((size_t)NB * cap * 8);
  u32* recs2 = (u32*)alloc((size_t)NB * cap * 4);
  (void)ws_size;
  (void)n_in;
  (void)out_size;

  hipMemsetAsync(cursor, 0, (size_t)NB * 4, stream);
  WPtrs wp;
  for (int i = 0; i < 10; ++i) wp.w[i] = Wm[i];
  pack_weights<<<10, 256, 0, stream>>>(wp, wpack);
  // bucket the edges (coalesced writes)
  multisplit<<<(E + MS_TILE - 1) / MS_TILE, 512, 0, stream>>>(rows, cols, vals, cursor, recs, E,
                                                             NB, cap);
  // row-sort each bucket in LDS -> per-row CSR with coalesced writes
  bucket_csr<<<NB, 512, 0, stream>>>(recs, cursor, recs2, rowstart, rowcnt, n, cap);
  int gblocks = (n + 31) / 32;  // 1563 blocks -> ~6/CU
  // x = mlp2(x_in, m1_*)  (fp32 input, fused 2-layer)
  mlp_fused<0><<<gblocks, 256, 0, stream>>>(x_in, wpack + 0 * 16384, Bm[0], wpack + 1 * 16384,
                                            Bm[1], x_b, n);
  // agg = segment_sum(vals * x[cols], rows)  (wave-per-row, register accum)
  spmm_agg<<<(n + 3) / 4, 256, 0, stream>>>(rowstart, rowcnt, recs2, x_b, agg_b, n);
  // out = mlp2(agg, m2_*)  (bf16 input, fused 2-layer)
  mlp_fused<1><<<gblocks, 256, 0, stream>>>(agg_b, wpack + 2 * 16384, Bm[2], wpack + 3 * 16384,
                                            Bm[3], agg_b, n);
  // gates + final fused (writes fp32 d_out directly)
  gates_final<<<gblocks, 256, 0, stream>>>(
      agg_b, x_b, wpack + 4 * 16384, wpack + 5 * 16384, wpack + 6 * 16384, wpack + 7 * 16384,
      wpack + 8 * 16384, wpack + 9 * 16384, Bm[4], Bm[5], Bm[6], Bm[7], Bm[8], Bm[9],
      (float*)d_out, n);
}

// Round 10
// 287.782 us; speedup vs baseline: 5.8886x; 1.0638x over previous
//
#include <hip/hip_runtime.h>

#define DD 128
#define BSHIFT 7
#define BROWS 128
#define MS_TILE 4096
#define MS_EPT 8       // edges per thread at 512 threads
#define STAGE_CAP 6144 // bucket_csr LDS stage capacity (>= cap)

typedef __attribute__((ext_vector_type(8))) short short8;
typedef __attribute__((ext_vector_type(4))) float f32x4;
typedef unsigned short u16;
typedef unsigned int u32;

__device__ __forceinline__ u16 f2bf(float f) {
  u32 u = __builtin_bit_cast(u32, f);
  u += 0x7fffu + ((u >> 16) & 1u);
  return (u16)(u >> 16);
}
__device__ __forceinline__ float bf2f(u16 s) {
  u32 u = ((u32)s) << 16;
  return __builtin_bit_cast(float, u);
}
__device__ __forceinline__ float f16val(u32 cv) {
  return (float)__builtin_bit_cast(_Float16, (u16)(cv & 0xffffu));
}
__device__ __forceinline__ float sigmoidf_(float v) { return 1.f / (1.f + __expf(-v)); }
__device__ __forceinline__ float tanhf_(float v) {
  float e = __expf(-2.f * v);
  return (1.f - e) / (1.f + e);
}

struct WPtrs { const float* w[10]; };

// Pack W [k][n] (row-major fp32, 128x128) into fragment-major bf16:
// Bp[((ks*8+nt)*64 + lane)*8 + e] = bf16( W[ks*32 + (lane>>4)*8 + e][(lane&15) + nt*16] )
__global__ void pack_weights(WPtrs wp, u16* __restrict__ bp) {
  const float* W = wp.w[blockIdx.x];
  u16* out = bp + (size_t)blockIdx.x * 16384;
  for (int o = threadIdx.x; o < 16384; o += blockDim.x) {
    int e = o & 7, lane = (o >> 3) & 63, nt = (o >> 9) & 7, ks = o >> 12;
    int k = ks * 32 + (lane >> 4) * 8 + e;
    int c = (lane & 15) + nt * 16;
    out[o] = f2bf(W[k * DD + c]);
  }
}

// LDS-staged multisplit: bucket edges by row>>BSHIFT into per-bucket spans of recs.
// rec = (col<<16 | fp16(val), row). Writes are contiguous per (tile,bucket) group.
__global__ __launch_bounds__(512) void multisplit(const int* __restrict__ rows,
                                                  const int* __restrict__ cols,
                                                  const float* __restrict__ vals,
                                                  int* __restrict__ cursor,
                                                  uint2* __restrict__ recs,
                                                  int E, int NB, int cap) {
  __shared__ u32 hist[512];
  __shared__ u32 scan_tmp[512];
  __shared__ u32 hbase[512];
  __shared__ int gbase[512];
  __shared__ u32 rankc[512];
  __shared__ uint2 stage[MS_TILE];
  const int t = threadIdx.x;
  const int tile0 = blockIdx.x * MS_TILE;
  hist[t] = 0;
  rankc[t] = 0;
  __syncthreads();
  int myb[MS_EPT];
  u32 mycv[MS_EPT], myrow[MS_EPT];
#pragma unroll
  for (int j = 0; j < MS_EPT; ++j) {
    int e = tile0 + j * 512 + t;
    if (e < E) {
      int r = rows[e];
      int b = r >> BSHIFT;
      myb[j] = b;
      myrow[j] = (u32)r;
      _Float16 hf = (_Float16)vals[e];
      mycv[j] = ((u32)cols[e] << 16) | (u32)__builtin_bit_cast(u16, hf);
      atomicAdd(&hist[b], 1u);
    } else {
      myb[j] = -1;
    }
  }
  __syncthreads();
  // exclusive scan of hist over 512 bins
  u32 v = hist[t];
  scan_tmp[t] = v;
  __syncthreads();
  for (int o = 1; o < 512; o <<= 1) {
    u32 x = (t >= o) ? scan_tmp[t - o] : 0;
    __syncthreads();
    scan_tmp[t] += x;
    __syncthreads();
  }
  hbase[t] = scan_tmp[t] - v;
  if (t < NB && v > 0) gbase[t] = atomicAdd(&cursor[t], (int)v);
  __syncthreads();
  // rank within (tile,bucket) and stage in bucket-sorted order
#pragma unroll
  for (int j = 0; j < MS_EPT; ++j) {
    if (myb[j] >= 0) {
      u32 rk = atomicAdd(&rankc[myb[j]], 1u);
      stage[hbase[myb[j]] + rk].x = mycv[j];
      stage[hbase[myb[j]] + rk].y = myrow[j];
    }
  }
  __syncthreads();
  int cnt = E - tile0;
  cnt = cnt < MS_TILE ? cnt : MS_TILE;
  for (int k = t; k < cnt; k += 512) {
    uint2 rec = stage[k];
    int b = (int)(rec.y >> BSHIFT);
    int off = gbase[b] + (k - (int)hbase[b]);
    if (off < cap) recs[(size_t)b * cap + off] = rec;
  }
}

// Per-bucket CSR: row-sort the bucket's records in LDS, write coalesced 4B records
// plus per-row start/count. One block per bucket.
__global__ __launch_bounds__(512) void bucket_csr(const uint2* __restrict__ recs,
                                                  const int* __restrict__ cursor,
                                                  u32* __restrict__ recs2,
                                                  int* __restrict__ rowstart,
                                                  int* __restrict__ rowcnt, int n, int cap) {
  __shared__ int hist[BROWS];
  __shared__ int sc[BROWS];
  __shared__ int hbase[BROWS];
  __shared__ u32 rank[BROWS];
  __shared__ u32 stage[STAGE_CAP];
  const int t = threadIdx.x;
  const int b = blockIdx.x;
  int cnt = cursor[b];
  cnt = cnt < cap ? cnt : cap;
  const uint2* rb = recs + (size_t)b * cap;
  if (t < BROWS) { hist[t] = 0; rank[t] = 0; }
  __syncthreads();
  for (int i = t; i < cnt; i += 512) atomicAdd(&hist[rb[i].y & (BROWS - 1)], 1);
  __syncthreads();
  // exclusive scan over 128 bins
  if (t < BROWS) sc[t] = hist[t];
  __syncthreads();
  for (int o = 1; o < BROWS; o <<= 1) {
    int x = (t >= o && t < BROWS) ? sc[t - o] : 0;
    __syncthreads();
    if (t < BROWS) sc[t] += x;
    __syncthreads();
  }
  if (t < BROWS) {
    hbase[t] = sc[t] - hist[t];
    int r = (b << BSHIFT) + t;
    if (r < n) {
      rowstart[r] = b * cap + hbase[t];
      rowcnt[r] = hist[t];
    }
  }
  __syncthreads();
  for (int i = t; i < cnt; i += 512) {
    uint2 rec = rb[i];
    int lr = (int)(rec.y & (BROWS - 1));
    u32 p = atomicAdd(&rank[lr], 1u);
    stage[hbase[lr] + p] = rec.x;
  }
  __syncthreads();
  u32* ob = recs2 + (size_t)b * cap;
  for (int i = t; i < cnt; i += 512) ob[i] = stage[i];
}

// wave per row; half-wave edge pairing: lanes 0-31 even edges, 32-63 odd edges.
// Each lane gathers 8B (4 bf16) of the 256B row -> one instruction covers 2 edges;
// 8-pair unroll = 16 edges (4KB) in flight per wave. Combine halves via shfl_xor.
__global__ void spmm_agg(const int* __restrict__ rowstart, const int* __restrict__ rowcnt,
                         const u32* __restrict__ recs2, const u16* __restrict__ xb,
                         u16* __restrict__ aggb, int n) {
  int row = blockIdx.x * 4 + (threadIdx.x >> 6);
  int lane = threadIdx.x & 63;
  if (row >= n) return;
  const int s = rowstart[row];
  const int cnt = rowcnt[row];
  const int hi = lane >> 5;
  const int l32 = lane & 31;
  float a0 = 0.f, a1 = 0.f, a2 = 0.f, a3 = 0.f;
  int j = 0;
#define SPMM_PAIR(P)                                                                   \
  {                                                                                    \
    u32 pk0 = recs2[s + j + 2 * (P)];                                                  \
    u32 pk1 = recs2[s + j + 2 * (P) + 1];                                              \
    u32 pk = hi ? pk1 : pk0;                                                           \
    uint2 xv = *(reinterpret_cast<const uint2*>(xb + (size_t)(pk >> 16) * DD) + l32);  \
    float vv = f16val(pk);                                                             \
    a0 += vv * bf2f((u16)(xv.x & 0xffffu));                                            \
    a1 += vv * bf2f((u16)(xv.x >> 16));                                                \
    a2 += vv * bf2f((u16)(xv.y & 0xffffu));                                            \
    a3 += vv * bf2f((u16)(xv.y >> 16));                                                \
  }
  for (; j + 15 < cnt; j += 16) {
    SPMM_PAIR(0) SPMM_PAIR(1) SPMM_PAIR(2) SPMM_PAIR(3)
    SPMM_PAIR(4) SPMM_PAIR(5) SPMM_PAIR(6) SPMM_PAIR(7)
  }
  for (; j + 1 < cnt; j += 2) { SPMM_PAIR(0) }
  if (j < cnt) {  // odd tail: hi half contributes 0 (address still valid)
    u32 pk0 = recs2[s + j];
    uint2 xv = *(reinterpret_cast<const uint2*>(xb + (size_t)(pk0 >> 16) * DD) + l32);
    float vv = hi ? 0.f : f16val(pk0);
    a0 += vv * bf2f((u16)(xv.x & 0xffffu));
    a1 += vv * bf2f((u16)(xv.x >> 16));
    a2 += vv * bf2f((u16)(xv.y & 0xffffu));
    a3 += vv * bf2f((u16)(xv.y >> 16));
  }
#undef SPMM_PAIR
  a0 += __shfl_xor(a0, 32, 64);
  a1 += __shfl_xor(a1, 32, 64);
  a2 += __shfl_xor(a2, 32, 64);
  a3 += __shfl_xor(a3, 32, 64);
  if (!hi) {
    uint2 o;
    o.x = ((u32)f2bf(a1) << 16) | (u32)f2bf(a0);
    o.y = ((u32)f2bf(a3) << 16) | (u32)f2bf(a2);
    *reinterpret_cast<uint2*>(aggb + (size_t)row * DD + l32 * 4) = o;
  }
}

// Fused 2-layer MLP, column-split: block = 32 rows, 4 waves as (m,c) =
// (row-tile, col-half). Each wave: 16 rows x 64 cols.
// ASRC 0: A is fp32; ASRC 1: A is bf16.
template <int ASRC>
__global__ __launch_bounds__(256) void mlp_fused(const void* __restrict__ Ain,
                                                 const u16* __restrict__ W1p,
                                                 const float* __restrict__ b1,
                                                 const u16* __restrict__ W2p,
                                                 const float* __restrict__ b2,
                                                 u16* __restrict__ outB, int n) {
  __shared__ u16 sm[32][136];
  const int lane = threadIdx.x & 63;
  const int wid = threadIdx.x >> 6;
  const int m = wid >> 1, c = wid & 1;
  const int row0 = blockIdx.x * 32 + m * 16;
  const int ar = lane & 15, ak = (lane >> 4) * 8;
  const int crow = 4 * (lane >> 4), ccol = lane & 15;

  f32x4 acc[4];
#pragma unroll
  for (int t = 0; t < 4; ++t) acc[t] = f32x4{0.f, 0.f, 0.f, 0.f};

#pragma unroll
  for (int ks = 0; ks < 4; ++ks) {
    short8 a;
    int r = row0 + ar;
    r = r < n ? r : n - 1;
    if (ASRC == 0) {
      const float* Ap = (const float*)Ain + (size_t)r * DD + ks * 32 + ak;
      float4 f0 = *reinterpret_cast<const float4*>(Ap);
      float4 f1 = *reinterpret_cast<const float4*>(Ap + 4);
      short8 tv;
      tv[0] = (short)f2bf(f0.x); tv[1] = (short)f2bf(f0.y);
      tv[2] = (short)f2bf(f0.z); tv[3] = (short)f2bf(f0.w);
      tv[4] = (short)f2bf(f1.x); tv[5] = (short)f2bf(f1.y);
      tv[6] = (short)f2bf(f1.z); tv[7] = (short)f2bf(f1.w);
      a = tv;
    } else {
      a = *reinterpret_cast<const short8*>((const u16*)Ain + (size_t)r * DD + ks * 32 + ak);
    }
#pragma unroll
    for (int nt4 = 0; nt4 < 4; ++nt4) {
      int nt = c * 4 + nt4;
      short8 bfr = *reinterpret_cast<const short8*>(W1p + (((ks * 8 + nt) * 64 + lane) * 8));
      acc[nt4] = __builtin_amdgcn_mfma_f32_16x16x32_bf16(a, bfr, acc[nt4], 0, 0, 0);
    }
  }
  // epilogue 1: bias + relu -> LDS (block tile, wave-disjoint quadrant)
#pragma unroll
  for (int nt4 = 0; nt4 < 4; ++nt4) {
    int col = (c * 4 + nt4) * 16 + ccol;
    float bsv = b1[col];
#pragma unroll
    for (int e = 0; e < 4; ++e) {
      float v = acc[nt4][e] + bsv;
      v = v > 0.f ? v : 0.f;
      sm[m * 16 + crow + e][col] = f2bf(v);
    }
  }
  __syncthreads();

  // GEMM2 from LDS (full K = 128 across both col-halves)
  f32x4 acc2[4];
#pragma unroll
  for (int t = 0; t < 4; ++t) acc2[t] = f32x4{0.f, 0.f, 0.f, 0.f};
#pragma unroll
  for (int ks = 0; ks < 4; ++ks) {
    short8 a2 = *reinterpret_cast<const short8*>(&sm[m * 16 + ar][ks * 32 + ak]);
#pragma unroll
    for (int nt4 = 0; nt4 < 4; ++nt4) {
      int nt = c * 4 + nt4;
      short8 bfr = *reinterpret_cast<const short8*>(W2p + (((ks * 8 + nt) * 64 + lane) * 8));
      acc2[nt4] = __builtin_amdgcn_mfma_f32_16x16x32_bf16(a2, bfr, acc2[nt4], 0, 0, 0);
    }
  }
#pragma unroll
  for (int nt4 = 0; nt4 < 4; ++nt4) {
    int col = (c * 4 + nt4) * 16 + ccol;
    float bsv = b2[col];
#pragma unroll
    for (int e = 0; e < 4; ++e) {
      int r = row0 + crow + e;
      if (r < n) outB[(size_t)r * DD + col] = f2bf(acc2[nt4][e] + bsv);
    }
  }
}

// Fully fused second-MLP + gates + final (out never touches HBM):
//   t2  = relu(agg@W3+b3)          -> LDS
//   out = t2@W4+b4                 -> LDS (bf16)
//   z   = sig(out@Wu1 + x@Wu2 + b); r = sig(out@Wr1 + x@Wr2 + b)
//   oi  = (out@Wo1 + bo1) + (r*x)@Wo2 + bo2   (rx via LDS)
//   result = (1-z)*x + z*tanh(oi)  -> fp32 d_out
__global__ __launch_bounds__(256) void mlp2_gates_final(
    const u16* __restrict__ Agg, const u16* __restrict__ Ax, const u16* __restrict__ W3p,
    const float* __restrict__ b3, const u16* __restrict__ W4p, const float* __restrict__ b4,
    const u16* __restrict__ Wu1p, const u16* __restrict__ Wu2p, const u16* __restrict__ Wr1p,
    const u16* __restrict__ Wr2p, const u16* __restrict__ Wo1p, const u16* __restrict__ Wo2p,
    const float* __restrict__ bu1, const float* __restrict__ bu2, const float* __restrict__ br1,
    const float* __restrict__ br2, const float* __restrict__ bo1, const float* __restrict__ bo2,
    float* __restrict__ out, int n) {
  __shared__ u16 sm[32][136];  // reused: t2 tile -> out tile -> rx tile
  const int lane = threadIdx.x & 63;
  const int wid = threadIdx.x >> 6;
  const int m = wid >> 1, c = wid & 1;
  const int row0 = blockIdx.x * 32 + m * 16;
  const int ar = lane & 15, ak = (lane >> 4) * 8;
  const int crow = 4 * (lane >> 4), ccol = lane & 15;

  // phase 1: t2 = relu(agg@W3 + b3) -> sm
  f32x4 acc[4];
#pragma unroll
  for (int t = 0; t < 4; ++t) acc[t] = f32x4{0.f, 0.f, 0.f, 0.f};
#pragma unroll
  for (int ks = 0; ks < 4; ++ks) {
    int r = row0 + ar;
    r = r < n ? r : n - 1;
    short8 a = *reinterpret_cast<const short8*>(Agg + (size_t)r * DD + ks * 32 + ak);
#pragma unroll
    for (int nt4 = 0; nt4 < 4; ++nt4) {
      int nt = c * 4 + nt4;
      short8 bfr = *reinterpret_cast<const short8*>(W3p + (((ks * 8 + nt) * 64 + lane) * 8));
      acc[nt4] = __builtin_amdgcn_mfma_f32_16x16x32_bf16(a, bfr, acc[nt4], 0, 0, 0);
    }
  }
#pragma unroll
  for (int nt4 = 0; nt4 < 4; ++nt4) {
    int col = (c * 4 + nt4) * 16 + ccol;
    float bsv = b3[col];
#pragma unroll
    for (int e = 0; e < 4; ++e) {
      float v = acc[nt4][e] + bsv;
      v = v > 0.f ? v : 0.f;
      sm[m * 16 + crow + e][col] = f2bf(v);
    }
  }
  __syncthreads();

  // phase 2: out = t2@W4 + b4 (keep in regs)
#pragma unroll
  for (int t = 0; t < 4; ++t) acc[t] = f32x4{0.f, 0.f, 0.f, 0.f};
#pragma unroll
  for (int ks = 0; ks < 4; ++ks) {
    short8 a2 = *reinterpret_cast<const short8*>(&sm[m * 16 + ar][ks * 32 + ak]);
#pragma unroll
    for (int nt4 = 0; nt4 < 4; ++nt4) {
      int nt = c * 4 + nt4;
      short8 bfr = *reinterpret_cast<const short8*>(W4p + (((ks * 8 + nt) * 64 + lane) * 8));
      acc[nt4] = __builtin_amdgcn_mfma_f32_16x16x32_bf16(a2, bfr, acc[nt4], 0, 0, 0);
    }
  }
  __syncthreads();  // all waves done reading t2 before overwriting sm
  // store out tile (bf16) -> sm
#pragma unroll
  for (int nt4 = 0; nt4 < 4; ++nt4) {
    int col = (c * 4 + nt4) * 16 + ccol;
    float bsv = b4[col];
#pragma unroll
    for (int e = 0; e < 4; ++e)
      sm[m * 16 + crow + e][col] = f2bf(acc[nt4][e] + bsv);
  }
  __syncthreads();

  // phase 3: gates. A-operands: out from LDS, x from global.
  f32x4 aZ[4], aR[4], aO[4];
#pragma unroll
  for (int t = 0; t < 4; ++t) {
    aZ[t] = f32x4{0.f, 0.f, 0.f, 0.f};
    aR[t] = f32x4{0.f, 0.f, 0.f, 0.f};
    aO[t] = f32x4{0.f, 0.f, 0.f, 0.f};
  }
#pragma unroll
  for (int ks = 0; ks < 4; ++ks) {
    int r = row0 + ar;
    r = r < n ? r : n - 1;
    short8 ao = *reinterpret_cast<const short8*>(&sm[m * 16 + ar][ks * 32 + ak]);
    short8 ax = *reinterpret_cast<const short8*>(Ax + (size_t)r * DD + ks * 32 + ak);
#pragma unroll
    for (int nt4 = 0; nt4 < 4; ++nt4) {
      int nt = c * 4 + nt4;
      size_t bo = (size_t)(((ks * 8 + nt) * 64 + lane) * 8);
      short8 b1 = *reinterpret_cast<const short8*>(Wu1p + bo);
      short8 b2 = *reinterpret_cast<const short8*>(Wu2p + bo);
      short8 b3f = *reinterpret_cast<const short8*>(Wr1p + bo);
      short8 b4f = *reinterpret_cast<const short8*>(Wr2p + bo);
      short8 b5 = *reinterpret_cast<const short8*>(Wo1p + bo);
      aZ[nt4] = __builtin_amdgcn_mfma_f32_16x16x32_bf16(ao, b1, aZ[nt4], 0, 0, 0);
      aZ[nt4] = __builtin_amdgcn_mfma_f32_16x16x32_bf16(ax, b2, aZ[nt4], 0, 0, 0);
      aR[nt4] = __builtin_amdgcn_mfma_f32_16x16x32_bf16(ao, b3f, aR[nt4], 0, 0, 0);
      aR[nt4] = __builtin_amdgcn_mfma_f32_16x16x32_bf16(ax, b4f, aR[nt4], 0, 0, 0);
      aO[nt4] = __builtin_amdgcn_mfma_f32_16x16x32_bf16(ao, b5, aO[nt4], 0, 0, 0);
    }
  }
  __syncthreads();  // done reading out tile before overwriting sm with rx
  // epilogue: z (keep f32 in aZ), oi1 (fold bias into aO), rx -> sm
#pragma unroll
  for (int nt4 = 0; nt4 < 4; ++nt4) {
    int col = (c * 4 + nt4) * 16 + ccol;
    float bz = bu1[col] + bu2[col];
    float br_ = br1[col] + br2[col];
    float bo_ = bo1[col];
#pragma unroll
    for (int e = 0; e < 4; ++e) {
      int r = row0 + crow + e;
      float z = sigmoidf_(aZ[nt4][e] + bz);
      float rr = sigmoidf_(aR[nt4][e] + br_);
      aZ[nt4][e] = z;
      aO[nt4][e] = aO[nt4][e] + bo_;
      float xv = 0.f;
      if (r < n) xv = bf2f(Ax[(size_t)r * DD + col]);
      sm[m * 16 + crow + e][col] = f2bf(rr * xv);
    }
  }
  __syncthreads();

  // phase 4: rx@Wo2 from LDS, final epilogue -> fp32 out
  f32x4 acc2[4];
#pragma unroll
  for (int t = 0; t < 4; ++t) acc2[t] = f32x4{0.f, 0.f, 0.f, 0.f};
#pragma unroll
  for (int ks = 0; ks < 4; ++ks) {
    short8 a2 = *reinterpret_cast<const short8*>(&sm[m * 16 + ar][ks * 32 + ak]);
#pragma unroll
    for (int nt4 = 0; nt4 < 4; ++nt4) {
      int nt = c * 4 + nt4;
      short8 bfr = *reinterpret_cast<const short8*>(Wo2p + (((ks * 8 + nt) * 64 + lane) * 8));
      acc2[nt4] = __builtin_amdgcn_mfma_f32_16x16x32_bf16(a2, bfr, acc2[nt4], 0, 0, 0);
    }
  }
#pragma unroll
  for (int nt4 = 0; nt4 < 4; ++nt4) {
    int col = (c * 4 + nt4) * 16 + ccol;
    float bo2v = bo2[col];
#pragma unroll
    for (int e = 0; e < 4; ++e) {
      int r = row0 + crow + e;
      if (r < n) {
        size_t idx = (size_t)r * DD + col;
        float oi = acc2[nt4][e] + bo2v + aO[nt4][e];
        float h = tanhf_(oi);
        float z = aZ[nt4][e];
        float xv = bf2f(Ax[idx]);
        out[idx] = (1.f - z) * xv + z * h;
      }
    }
  }
}

extern "C" void kernel_launch(void* const* d_in, const int* in_sizes, int n_in,
                              void* d_out, int out_size, void* d_ws, size_t ws_size,
                              hipStream_t stream) {
  const int n = in_sizes[0] / DD;  // 50000
  const int E = in_sizes[1];       // 1.6M
  const float* x_in = (const float*)d_in[0];
  const int* rows = (const int*)d_in[1];
  const int* cols = (const int*)d_in[2];
  const float* vals = (const float*)d_in[3];
  const float* Wm[10];
  const float* Bm[10];
  for (int i = 0; i < 10; ++i) {
    Wm[i] = (const float*)d_in[4 + 2 * i];
    Bm[i] = (const float*)d_in[5 + 2 * i];
  }

  const int NB = (n + BROWS - 1) >> BSHIFT;           // 391
  int cap = (((E / NB) * 5) / 4 + 511) & ~511;        // ~5120, 16-sigma slack
  cap = cap < STAGE_CAP ? cap : STAGE_CAP;

  char* base = (char*)d_ws;
  size_t off = 0;
  auto alloc = [&](size_t bytes) -> char* {
    char* p = base + off;
    off += (bytes + 255) & ~(size_t)255;
    return p;
  };
  u16* wpack = (u16*)alloc((size_t)10 * 16384 * 2);
  u16* x_b = (u16*)alloc((size_t)n * DD * 2);
  u16* agg_b = (u16*)alloc((size_t)n * DD * 2);
  int* cursor = (int*)alloc((size_t)NB * 4);
  int* rowstart = (int*)alloc((size_t)n * 4);
  int* rowcnt = (int*)alloc((size_t)n * 4);
  uint2* recs = (uint2*)alloc((size_t)NB * cap * 8);
  u32* recs2 = (u32*)alloc((size_t)NB * cap * 4);
  (void)ws_size;
  (void)n_in;
  (void)out_size;

  hipMemsetAsync(cursor, 0, (size_t)NB * 4, stream);
  WPtrs wp;
  for (int i = 0; i < 10; ++i) wp.w[i] = Wm[i];
  pack_weights<<<10, 256, 0, stream>>>(wp, wpack);
  // bucket the edges (coalesced writes)
  multisplit<<<(E + MS_TILE - 1) / MS_TILE, 512, 0, stream>>>(rows, cols, vals, cursor, recs, E,
                                                             NB, cap);
  // row-sort each bucket in LDS -> per-row CSR with coalesced writes
  bucket_csr<<<NB, 512, 0, stream>>>(recs, cursor, recs2, rowstart, rowcnt, n, cap);
  int gblocks = (n + 31) / 32;  // 1563 blocks
  // x = mlp2(x_in, m1_*)  (fp32 input, fused 2-layer)
  mlp_fused<0><<<gblocks, 256, 0, stream>>>(x_in, wpack + 0 * 16384, Bm[0], wpack + 1 * 16384,
                                            Bm[1], x_b, n);
  // agg = segment_sum(vals * x[cols], rows)  (half-wave paired gather)
  spmm_agg<<<(n + 3) / 4, 256, 0, stream>>>(rowstart, rowcnt, recs2, x_b, agg_b, n);
  // out-MLP + gates + final fully fused (out never hits HBM)
  mlp2_gates_final<<<gblocks, 256, 0, stream>>>(
      agg_b, x_b, wpack + 2 * 16384, Bm[2], wpack + 3 * 16384, Bm[3], wpack + 4 * 16384,
      wpack + 5 * 16384, wpack + 6 * 16384, wpack + 7 * 16384, wpack + 8 * 16384,
      wpack + 9 * 16384, Bm[4], Bm[5], Bm[6], Bm[7], Bm[8], Bm[9], (float*)d_out, n);
}